// Round 1
// baseline (1657.558 us; speedup 1.0000x reference)
//
#include <hip/hip_runtime.h>

// Problem constants
#define BB 4
#define LL 4096
#define DD 768
#define TD 2304          // 3*D
#define NFFT 8192
#define LOG2N 13

__device__ __forceinline__ int brev13(int t) {
    return (int)(__brev((unsigned)t) >> 19);
}

// ---------------------------------------------------------------------------
// K1: in-projection GEMM (NT): C[m][n] = sum_k A[m][k]*Bw[n][k] + bias[n]
// A = u (16384 x 768), Bw = w_in (2304 x 768), C = x (16384 x 2304)
// 128x128x16 tile, 256 threads, 8x8 micro-tile
// ---------------------------------------------------------------------------
__global__ __launch_bounds__(256) void k_gemm_nt128(
        const float* __restrict__ A, const float* __restrict__ Bw,
        const float* __restrict__ bias, float* __restrict__ C,
        int N, int K) {
    __shared__ float As[16][128];
    __shared__ float Bs[16][128];
    const int tid = threadIdx.x;
    const int m0 = blockIdx.y * 128;
    const int n0 = blockIdx.x * 128;
    const int tx = tid & 15;
    const int ty = tid >> 4;
    const int row0 = tid >> 1;          // 0..127
    const int kg0  = (tid & 1) * 2;     // float4 group 0 or 2
    float acc[8][8] = {};
    for (int k0 = 0; k0 < K; k0 += 16) {
#pragma unroll
        for (int h = 0; h < 2; ++h) {
            int grp = kg0 + h;
            float4 a4 = *(const float4*)(A + (size_t)(m0 + row0) * K + k0 + grp * 4);
            As[grp*4+0][row0] = a4.x; As[grp*4+1][row0] = a4.y;
            As[grp*4+2][row0] = a4.z; As[grp*4+3][row0] = a4.w;
            float4 b4 = *(const float4*)(Bw + (size_t)(n0 + row0) * K + k0 + grp * 4);
            Bs[grp*4+0][row0] = b4.x; Bs[grp*4+1][row0] = b4.y;
            Bs[grp*4+2][row0] = b4.z; Bs[grp*4+3][row0] = b4.w;
        }
        __syncthreads();
#pragma unroll
        for (int kk = 0; kk < 16; ++kk) {
            float4 a0 = *(const float4*)&As[kk][ty*8];
            float4 a1 = *(const float4*)&As[kk][ty*8+4];
            float4 b0 = *(const float4*)&Bs[kk][tx*8];
            float4 b1 = *(const float4*)&Bs[kk][tx*8+4];
            float a[8] = {a0.x,a0.y,a0.z,a0.w,a1.x,a1.y,a1.z,a1.w};
            float b[8] = {b0.x,b0.y,b0.z,b0.w,b1.x,b1.y,b1.z,b1.w};
#pragma unroll
            for (int i = 0; i < 8; ++i)
#pragma unroll
                for (int j = 0; j < 8; ++j)
                    acc[i][j] += a[i] * b[j];
        }
        __syncthreads();
    }
#pragma unroll
    for (int i = 0; i < 8; ++i) {
        int m = m0 + ty*8 + i;
#pragma unroll
        for (int j = 0; j < 8; ++j)
            C[(size_t)m * N + n0 + tx*8 + j] = acc[i][j] + bias[n0 + tx*8 + j];
    }
}

// ---------------------------------------------------------------------------
// K2: depthwise short conv (k=3, causal with lookback 2) + gating + transpose
// in:  x (B, L, 3D) ; out: vbuf (B,D,L) = v*x1 ; x2buf (B,D,L) = x2
// block: 64 l x 32 d tile
// ---------------------------------------------------------------------------
__global__ __launch_bounds__(256) void k_shortconv(
        const float* __restrict__ x, const float* __restrict__ conv_w,
        const float* __restrict__ conv_b,
        float* __restrict__ vbuf, float* __restrict__ x2buf) {
    __shared__ float xs[3][32][66];
    const int l0 = blockIdx.x * 64;
    const int d0 = blockIdx.y * 32;
    const int b  = blockIdx.z;
    const int tid = threadIdx.x;
    for (int idx = tid; idx < 3 * 66 * 32; idx += 256) {
        int g  = idx / (66 * 32);
        int r  = idx % (66 * 32);
        int ll = r >> 5;
        int dd = r & 31;
        int gl = l0 - 2 + ll;
        float val = 0.f;
        if (gl >= 0) val = x[((size_t)(b * LL + gl)) * TD + g * DD + d0 + dd];
        xs[g][dd][ll] = val;
    }
    __syncthreads();
    const int tl  = tid & 63;
    const int tdq = tid >> 6;
    for (int dd = tdq; dd < 32; dd += 4) {
        int c0 = d0 + dd;
        const float* w0 = conv_w + (size_t)c0 * 3;
        const float* w1 = conv_w + (size_t)(DD + c0) * 3;
        const float* w2 = conv_w + (size_t)(2 * DD + c0) * 3;
        float x1v = w0[0]*xs[0][dd][tl] + w0[1]*xs[0][dd][tl+1] + w0[2]*xs[0][dd][tl+2] + conv_b[c0];
        float x2v = w1[0]*xs[1][dd][tl] + w1[1]*xs[1][dd][tl+1] + w1[2]*xs[1][dd][tl+2] + conv_b[DD + c0];
        float vv  = w2[0]*xs[2][dd][tl] + w2[1]*xs[2][dd][tl+1] + w2[2]*xs[2][dd][tl+2] + conv_b[2*DD + c0];
        size_t o = ((size_t)(b * DD + c0)) * LL + l0 + tl;
        vbuf[o]  = vv * x1v;
        x2buf[o] = x2v;
    }
}

// ---------------------------------------------------------------------------
// K3a: implicit filter MLP (3->16->16->16 with shared Sin), per position l
// ---------------------------------------------------------------------------
__global__ __launch_bounds__(256) void k_filter_mlp(
        const float* __restrict__ z,
        const float* __restrict__ fw1, const float* __restrict__ fb1,
        const float* __restrict__ fw2, const float* __restrict__ fb2,
        const float* __restrict__ fw3, const float* __restrict__ fb3,
        const float* __restrict__ freq, float* __restrict__ h3g) {
    int l = blockIdx.x * 256 + threadIdx.x;
    float z0 = z[l*3+0], z1 = z[l*3+1], z2 = z[l*3+2];
    float h1[16], h2[16];
#pragma unroll
    for (int j = 0; j < 16; ++j) {
        float a = z0*fw1[j*3+0] + z1*fw1[j*3+1] + z2*fw1[j*3+2] + fb1[j];
        h1[j] = sinf(freq[j] * a);
    }
#pragma unroll
    for (int j = 0; j < 16; ++j) {
        float a = fb2[j];
#pragma unroll
        for (int i = 0; i < 16; ++i) a += h1[i] * fw2[j*16+i];
        h2[j] = sinf(freq[j] * a);
    }
#pragma unroll
    for (int j = 0; j < 16; ++j) {
        float a = fb3[j];
#pragma unroll
        for (int i = 0; i < 16; ++i) a += h2[i] * fw3[j*16+i];
        h3g[l*16+j] = sinf(freq[j] * a);
    }
}

// ---------------------------------------------------------------------------
// K3b: k[d][l] = (h3[l] . fw4[d]) * exp(-t_l * |delta_d|)
// ---------------------------------------------------------------------------
__global__ __launch_bounds__(256) void k_filter_k(
        const float* __restrict__ h3g, const float* __restrict__ fw4,
        float* __restrict__ kt) {
    const int d = blockIdx.y;
    const int l = blockIdx.x * 256 + threadIdx.x;
    float acc = 0.f;
#pragma unroll
    for (int j = 0; j < 16; ++j) acc += h3g[l*16+j] * fw4[d*16+j];
    float t = (float)l / 4095.0f;
    const float min_d = -3.070113457325394f;   // ln(0.01)/1.5
    const float max_d = -15.35056728662697f;   // ln(0.01)/0.3
    float delta = min_d + (max_d - min_d) * ((float)d / 767.0f);
    acc *= expf(-t * fabsf(delta));
    kt[(size_t)d * LL + l] = acc;
}

// ---------------------------------------------------------------------------
// K3c: FFT of filter rows -> kf[d][0..8191] = DFT(k_d)/8192 (full complex)
// radix-2 DIT, bit-reversed load, 256 threads / row
// ---------------------------------------------------------------------------
__global__ __launch_bounds__(256) void k_fft_filter(
        const float* __restrict__ kt, float2* __restrict__ kf) {
    __shared__ float re[NFFT], im[NFFT];
    const int d = blockIdx.x, tid = threadIdx.x;
    for (int t = tid; t < NFFT; t += 256) {
        int rv = brev13(t);
        re[rv] = (t < LL) ? kt[(size_t)d * LL + t] : 0.f;
        im[rv] = 0.f;
    }
    for (int s = 1; s <= LOG2N; ++s) {
        int half = 1 << (s - 1);
        __syncthreads();
        for (int j = tid; j < NFFT/2; j += 256) {
            int pos = j & (half - 1);
            int i1 = ((j >> (s - 1)) << s) | pos;
            int i2 = i1 + half;
            float ang = -3.14159265358979f * (float)pos / (float)half;
            float wr, wi; __sincosf(ang, &wi, &wr);
            float xr = re[i2], xi = im[i2];
            float tr = wr*xr - wi*xi, ti = wr*xi + wi*xr;
            float ur = re[i1], ui = im[i1];
            re[i1] = ur + tr; im[i1] = ui + ti;
            re[i2] = ur - tr; im[i2] = ui - ti;
        }
    }
    __syncthreads();
    const float inv_n = 1.0f / (float)NFFT;
    for (int t = tid; t < NFFT; t += 256)
        kf[(size_t)d * NFFT + t] = make_float2(re[t]*inv_n, im[t]*inv_n);
}

// ---------------------------------------------------------------------------
// K4: per-(b,d) FFT conv: y = IDFT(V .* kf), out = (y + v*bias)*x2 in place
// forward DIT (bitrev in -> natural), conj-multiply, forward DIF
// (natural in -> bitrev out), read real part at brev(t).
// ---------------------------------------------------------------------------
__global__ __launch_bounds__(256) void k_fftconv(
        const float* __restrict__ vbuf, const float2* __restrict__ kf,
        const float* __restrict__ fbias, float* __restrict__ x2y) {
    __shared__ float re[NFFT], im[NFFT];
    const int bd = blockIdx.x;
    const int d  = bd % DD;
    const int tid = threadIdx.x;
    const float* v = vbuf + (size_t)bd * LL;
    for (int t = tid; t < NFFT; t += 256) {
        int rv = brev13(t);
        re[rv] = (t < LL) ? v[t] : 0.f;
        im[rv] = 0.f;
    }
    // forward DIT
    for (int s = 1; s <= LOG2N; ++s) {
        int half = 1 << (s - 1);
        __syncthreads();
        for (int j = tid; j < NFFT/2; j += 256) {
            int pos = j & (half - 1);
            int i1 = ((j >> (s - 1)) << s) | pos;
            int i2 = i1 + half;
            float ang = -3.14159265358979f * (float)pos / (float)half;
            float wr, wi; __sincosf(ang, &wi, &wr);
            float xr = re[i2], xi = im[i2];
            float tr = wr*xr - wi*xi, ti = wr*xi + wi*xr;
            float ur = re[i1], ui = im[i1];
            re[i1] = ur + tr; im[i1] = ui + ti;
            re[i2] = ur - tr; im[i2] = ui - ti;
        }
    }
    __syncthreads();
    // multiply by kf and conjugate (for inverse-via-forward trick)
    for (int t = tid; t < NFFT; t += 256) {
        float2 w = kf[(size_t)d * NFFT + t];
        float ar = re[t], ai = im[t];
        float pr = ar*w.x - ai*w.y;
        float pi = ar*w.y + ai*w.x;
        re[t] = pr; im[t] = -pi;
    }
    // forward DIF: natural order in, bit-reversed out
    for (int s = LOG2N; s >= 1; --s) {
        int half = 1 << (s - 1);
        __syncthreads();
        for (int j = tid; j < NFFT/2; j += 256) {
            int pos = j & (half - 1);
            int i1 = ((j >> (s - 1)) << s) | pos;
            int i2 = i1 + half;
            float ur = re[i1], ui = im[i1];
            float vr = re[i2], vi = im[i2];
            re[i1] = ur + vr; im[i1] = ui + vi;
            float dr = ur - vr, di = ui - vi;
            float ang = -3.14159265358979f * (float)pos / (float)half;
            float wr, wi; __sincosf(ang, &wi, &wr);
            re[i2] = wr*dr - wi*di;
            im[i2] = wr*di + wi*dr;
        }
    }
    __syncthreads();
    const float fb = fbias[d];
    float* x2p = x2y + (size_t)bd * LL;
    for (int t = tid; t < LL; t += 256) {
        float y = re[brev13(t)];            // Re(conj(Q)) == Re(Q)
        float val = (y + v[t] * fb) * x2p[t];
        x2p[t] = val;
    }
}

// ---------------------------------------------------------------------------
// K5: out-projection GEMM (TN): C[m][n] = sum_k AT[k][m]*Wo[n][k] + bias[n]
// AT = gated y in (B, D, L) layout; m=(b,l); C = d_out (16384 x 768)
// ---------------------------------------------------------------------------
__global__ __launch_bounds__(256) void k_out_gemm(
        const float* __restrict__ YG, const float* __restrict__ Wo,
        const float* __restrict__ bias, float* __restrict__ C) {
    __shared__ float As[16][128];
    __shared__ float Bs[16][128];
    const int tid = threadIdx.x;
    const int m0 = blockIdx.y * 128;
    const int n0 = blockIdx.x * 128;
    const int bidx = m0 >> 12;          // m0 / 4096
    const int l0 = m0 & 4095;
    const int tx = tid & 15;
    const int ty = tid >> 4;
    const int row0 = tid >> 1;
    const int kg0 = (tid & 1) * 2;
    float acc[8][8] = {};
    for (int k0 = 0; k0 < DD; k0 += 16) {
#pragma unroll
        for (int h = 0; h < 2; ++h) {
            int k = (tid >> 5) + h * 8;
            int m = (tid & 31) * 4;
            float4 a4 = *(const float4*)(YG + ((size_t)(bidx * DD + k0 + k)) * LL + l0 + m);
            *(float4*)&As[k][m] = a4;
        }
#pragma unroll
        for (int h = 0; h < 2; ++h) {
            int grp = kg0 + h;
            float4 b4 = *(const float4*)(Wo + (size_t)(n0 + row0) * DD + k0 + grp * 4);
            Bs[grp*4+0][row0] = b4.x; Bs[grp*4+1][row0] = b4.y;
            Bs[grp*4+2][row0] = b4.z; Bs[grp*4+3][row0] = b4.w;
        }
        __syncthreads();
#pragma unroll
        for (int kk = 0; kk < 16; ++kk) {
            float4 a0 = *(const float4*)&As[kk][ty*8];
            float4 a1 = *(const float4*)&As[kk][ty*8+4];
            float4 b0 = *(const float4*)&Bs[kk][tx*8];
            float4 b1 = *(const float4*)&Bs[kk][tx*8+4];
            float a[8] = {a0.x,a0.y,a0.z,a0.w,a1.x,a1.y,a1.z,a1.w};
            float b[8] = {b0.x,b0.y,b0.z,b0.w,b1.x,b1.y,b1.z,b1.w};
#pragma unroll
            for (int i = 0; i < 8; ++i)
#pragma unroll
                for (int j = 0; j < 8; ++j)
                    acc[i][j] += a[i] * b[j];
        }
        __syncthreads();
    }
#pragma unroll
    for (int i = 0; i < 8; ++i) {
        int m = m0 + ty*8 + i;
#pragma unroll
        for (int j = 0; j < 8; ++j)
            C[(size_t)m * DD + n0 + tx*8 + j] = acc[i][j] + bias[n0 + tx*8 + j];
    }
}

// ---------------------------------------------------------------------------
extern "C" void kernel_launch(void* const* d_in, const int* in_sizes, int n_in,
                              void* d_out, int out_size, void* d_ws, size_t ws_size,
                              hipStream_t stream) {
    const float* u      = (const float*)d_in[0];
    const float* w_in   = (const float*)d_in[1];
    const float* b_in   = (const float*)d_in[2];
    const float* w_out  = (const float*)d_in[3];
    const float* b_out  = (const float*)d_in[4];
    const float* conv_w = (const float*)d_in[5];
    const float* conv_b = (const float*)d_in[6];
    const float* z      = (const float*)d_in[7];
    const float* fw1    = (const float*)d_in[8];
    const float* fb1    = (const float*)d_in[9];
    const float* fw2    = (const float*)d_in[10];
    const float* fb2    = (const float*)d_in[11];
    const float* fw3    = (const float*)d_in[12];
    const float* fb3    = (const float*)d_in[13];
    const float* fw4    = (const float*)d_in[14];
    const float* freq   = (const float*)d_in[15];
    const float* fbias  = (const float*)d_in[16];

    char* ws = (char*)d_ws;
    // layout: [ x : 151MB ][ v : 50.3MB ][ x2/y : 50.3MB ]
    // after x is dead (post K2), its region is reused for kf / h3 / kt
    float*  x    = (float*)(ws);                          // 150,994,944 B
    float*  vbuf = (float*)(ws + 150994944);              //  50,331,648 B
    float*  x2y  = (float*)(ws + 201326592);              //  50,331,648 B
    float2* kf   = (float2*)(ws);                         //  50,331,648 B (alias x)
    float*  h3g  = (float*)(ws + 50331648);               //     262,144 B (alias x)
    float*  kt   = (float*)(ws + 50593792);               //  12,582,912 B (alias x)

    // 1) x = u @ w_in^T + b_in              (B,L,3D)
    k_gemm_nt128<<<dim3(TD/128, (BB*LL)/128), 256, 0, stream>>>(u, w_in, b_in, x, TD, DD);
    // 2) short conv + pre-gate; transpose to (B,D,L)
    k_shortconv<<<dim3(LL/64, DD/32, BB), 256, 0, stream>>>(x, conv_w, conv_b, vbuf, x2y);
    // 3) filter: MLP -> k(d,l) -> FFT (these alias x's region; run after K2)
    k_filter_mlp<<<LL/256, 256, 0, stream>>>(z, fw1, fb1, fw2, fb2, fw3, fb3, freq, h3g);
    k_filter_k<<<dim3(LL/256, DD), 256, 0, stream>>>(h3g, fw4, kt);
    k_fft_filter<<<DD, 256, 0, stream>>>(kt, kf);
    // 4) FFT long conv + bias + post-gate (in place over x2y)
    k_fftconv<<<BB*DD, 256, 0, stream>>>(vbuf, kf, fbias, x2y);
    // 5) out = y_g @ w_out^T + b_out
    k_out_gemm<<<dim3(DD/128, (BB*LL)/128), 256, 0, stream>>>(x2y, w_out, b_out, (float*)d_out);
}

// Round 2
// 926.911 us; speedup vs baseline: 1.7883x; 1.7883x over previous
//
#include <hip/hip_runtime.h>

// Problem constants
#define BB 4
#define LL 4096
#define DD 768
#define TD 2304          // 3*D
#define NFFT 8192
#define LOG2N 13

__device__ __forceinline__ int brev13(int t) {
    return (int)(__brev((unsigned)t) >> 19);
}

__device__ __forceinline__ unsigned short f2b(float f) {
    unsigned u = __float_as_uint(f);
    unsigned r = (u + 0x7fffu + ((u >> 16) & 1u)) >> 16;
    return (unsigned short)r;
}

typedef __bf16 bf16x8 __attribute__((ext_vector_type(8)));
typedef float  f32x4  __attribute__((ext_vector_type(4)));

// ---------------------------------------------------------------------------
// K0: fp32 -> bf16 cast (two sources fused), float4 granularity
// ---------------------------------------------------------------------------
__global__ __launch_bounds__(256) void k_cast_pair(
        const float* __restrict__ srcA, unsigned long long nA4,
        const float* __restrict__ srcB, unsigned long long nB4,
        unsigned short* __restrict__ dstA, unsigned short* __restrict__ dstB) {
    unsigned long long i = (unsigned long long)blockIdx.x * 256 + threadIdx.x;
    const float* s; unsigned short* d;
    if (i < nA4)            { s = srcA + i * 4;         d = dstA + i * 4; }
    else if (i < nA4 + nB4) { unsigned long long j = i - nA4; s = srcB + j * 4; d = dstB + j * 4; }
    else return;
    float4 v = *(const float4*)s;
    unsigned long long p = (unsigned long long)f2b(v.x)
                         | ((unsigned long long)f2b(v.y) << 16)
                         | ((unsigned long long)f2b(v.z) << 32)
                         | ((unsigned long long)f2b(v.w) << 48);
    *(unsigned long long*)d = p;
}

// ---------------------------------------------------------------------------
// K1: bf16 MFMA GEMM (NT): C[m][n] = sum_k A[m][k]*Bw[n][k] + bias[n]
// A (M x K) bf16 row-major, Bw (N x K) bf16 row-major, C fp32 (M x N).
// 128x128 tile, BK=32, 256 thr = 4 waves, each wave 64x64 via 4x4 MFMAs.
// m97 structure: global_load_lds width 16 staging, ds_read_b128 fragments.
// ---------------------------------------------------------------------------
__global__ __launch_bounds__(256) void k_gemm_mfma(
        const unsigned short* __restrict__ A, const unsigned short* __restrict__ Bw,
        const float* __restrict__ bias, float* __restrict__ C,
        int N, int K) {
    __shared__ unsigned char AsB[8192];
    __shared__ unsigned char BsB[8192];
    const int tid  = threadIdx.x;
    const int lane = tid & 63;
    const int w    = tid >> 6;
    const int wr   = w >> 1, wc = w & 1;
    const int m0 = blockIdx.y * 128, n0 = blockIdx.x * 128;
    f32x4 acc[4][4] = {};
    const int rowIn = lane >> 2;     // 0..15 within 16-row chunk
    const int k16   = lane & 3;      // which 16B piece of the 64B row
    for (int k0 = 0; k0 < K; k0 += 32) {
#pragma unroll
        for (int c = 0; c < 2; ++c) {
            int chunk = w * 2 + c;               // wave-uniform
            int row = chunk * 16 + rowIn;
            const char* ga = (const char*)A  + (((size_t)(m0 + row) * K + k0) * 2) + k16 * 16;
            __builtin_amdgcn_global_load_lds(
                (const __attribute__((address_space(1))) void*)ga,
                (__attribute__((address_space(3))) void*)(AsB + chunk * 1024), 16, 0, 0);
            const char* gb = (const char*)Bw + (((size_t)(n0 + row) * K + k0) * 2) + k16 * 16;
            __builtin_amdgcn_global_load_lds(
                (const __attribute__((address_space(1))) void*)gb,
                (__attribute__((address_space(3))) void*)(BsB + chunk * 1024), 16, 0, 0);
        }
        __syncthreads();
        const int koff = (lane >> 4) * 16;       // quad*8 bf16 = 16 B
        const int rsel = lane & 15;
        bf16x8 af[4], bfr[4];
#pragma unroll
        for (int i = 0; i < 4; ++i) {
            af[i]  = *(const bf16x8*)(AsB + (wr * 64 + i * 16 + rsel) * 64 + koff);
            bfr[i] = *(const bf16x8*)(BsB + (wc * 64 + i * 16 + rsel) * 64 + koff);
        }
#pragma unroll
        for (int i = 0; i < 4; ++i)
#pragma unroll
            for (int j = 0; j < 4; ++j)
                acc[i][j] = __builtin_amdgcn_mfma_f32_16x16x32_bf16(af[i], bfr[j], acc[i][j], 0, 0, 0);
        __syncthreads();
    }
    const int cq = lane >> 4;
    const int cn = lane & 15;
#pragma unroll
    for (int j = 0; j < 4; ++j) {
        int col = n0 + wc * 64 + j * 16 + cn;
        float bv = bias[col];
#pragma unroll
        for (int i = 0; i < 4; ++i) {
            int rbase = m0 + wr * 64 + i * 16 + cq * 4;
#pragma unroll
            for (int r = 0; r < 4; ++r)
                C[(size_t)(rbase + r) * N + col] = acc[i][j][r] + bv;
        }
    }
}

// ---------------------------------------------------------------------------
// K2: depthwise short conv (k=3, causal lookback 2) + gating + transpose
// in:  x (B, L, 3D) fp32 ; out: vbuf (B,D,L) = v*x1 ; x2buf (B,D,L) = x2
// ---------------------------------------------------------------------------
__global__ __launch_bounds__(256) void k_shortconv(
        const float* __restrict__ x, const float* __restrict__ conv_w,
        const float* __restrict__ conv_b,
        float* __restrict__ vbuf, float* __restrict__ x2buf) {
    __shared__ float xs[3][32][66];
    const int l0 = blockIdx.x * 64;
    const int d0 = blockIdx.y * 32;
    const int b  = blockIdx.z;
    const int tid = threadIdx.x;
    for (int idx = tid; idx < 3 * 66 * 32; idx += 256) {
        int g  = idx / (66 * 32);
        int r  = idx % (66 * 32);
        int ll = r >> 5;
        int dd = r & 31;
        int gl = l0 - 2 + ll;
        float val = 0.f;
        if (gl >= 0) val = x[((size_t)(b * LL + gl)) * TD + g * DD + d0 + dd];
        xs[g][dd][ll] = val;
    }
    __syncthreads();
    const int tl  = tid & 63;
    const int tdq = tid >> 6;
    for (int dd = tdq; dd < 32; dd += 4) {
        int c0 = d0 + dd;
        const float* w0 = conv_w + (size_t)c0 * 3;
        const float* w1 = conv_w + (size_t)(DD + c0) * 3;
        const float* w2 = conv_w + (size_t)(2 * DD + c0) * 3;
        float x1v = w0[0]*xs[0][dd][tl] + w0[1]*xs[0][dd][tl+1] + w0[2]*xs[0][dd][tl+2] + conv_b[c0];
        float x2v = w1[0]*xs[1][dd][tl] + w1[1]*xs[1][dd][tl+1] + w1[2]*xs[1][dd][tl+2] + conv_b[DD + c0];
        float vv  = w2[0]*xs[2][dd][tl] + w2[1]*xs[2][dd][tl+1] + w2[2]*xs[2][dd][tl+2] + conv_b[2*DD + c0];
        size_t o = ((size_t)(b * DD + c0)) * LL + l0 + tl;
        vbuf[o]  = vv * x1v;
        x2buf[o] = x2v;
    }
}

// ---------------------------------------------------------------------------
// K3a: implicit filter MLP (3->16->16->16 with shared Sin), per position l
// ---------------------------------------------------------------------------
__global__ __launch_bounds__(256) void k_filter_mlp(
        const float* __restrict__ z,
        const float* __restrict__ fw1, const float* __restrict__ fb1,
        const float* __restrict__ fw2, const float* __restrict__ fb2,
        const float* __restrict__ fw3, const float* __restrict__ fb3,
        const float* __restrict__ freq, float* __restrict__ h3g) {
    int l = blockIdx.x * 256 + threadIdx.x;
    float z0 = z[l*3+0], z1 = z[l*3+1], z2 = z[l*3+2];
    float h1[16], h2[16];
#pragma unroll
    for (int j = 0; j < 16; ++j) {
        float a = z0*fw1[j*3+0] + z1*fw1[j*3+1] + z2*fw1[j*3+2] + fb1[j];
        h1[j] = sinf(freq[j] * a);
    }
#pragma unroll
    for (int j = 0; j < 16; ++j) {
        float a = fb2[j];
#pragma unroll
        for (int i = 0; i < 16; ++i) a += h1[i] * fw2[j*16+i];
        h2[j] = sinf(freq[j] * a);
    }
#pragma unroll
    for (int j = 0; j < 16; ++j) {
        float a = fb3[j];
#pragma unroll
        for (int i = 0; i < 16; ++i) a += h2[i] * fw3[j*16+i];
        h3g[l*16+j] = sinf(freq[j] * a);
    }
}

// ---------------------------------------------------------------------------
// K3b: k[d][l] = (h3[l] . fw4[d]) * exp(-t_l * |delta_d|)
// ---------------------------------------------------------------------------
__global__ __launch_bounds__(256) void k_filter_k(
        const float* __restrict__ h3g, const float* __restrict__ fw4,
        float* __restrict__ kt) {
    const int d = blockIdx.y;
    const int l = blockIdx.x * 256 + threadIdx.x;
    float acc = 0.f;
#pragma unroll
    for (int j = 0; j < 16; ++j) acc += h3g[l*16+j] * fw4[d*16+j];
    float t = (float)l / 4095.0f;
    const float min_d = -3.070113457325394f;   // ln(0.01)/1.5
    const float max_d = -15.35056728662697f;   // ln(0.01)/0.3
    float delta = min_d + (max_d - min_d) * ((float)d / 767.0f);
    acc *= expf(-t * fabsf(delta));
    kt[(size_t)d * LL + l] = acc;
}

// ---------------------------------------------------------------------------
// K3c: FFT of filter rows -> kf[d][0..8191] = DFT(k_d)/8192 (full complex)
// ---------------------------------------------------------------------------
__global__ __launch_bounds__(256) void k_fft_filter(
        const float* __restrict__ kt, float2* __restrict__ kf) {
    __shared__ float re[NFFT], im[NFFT];
    const int d = blockIdx.x, tid = threadIdx.x;
    for (int t = tid; t < NFFT; t += 256) {
        int rv = brev13(t);
        re[rv] = (t < LL) ? kt[(size_t)d * LL + t] : 0.f;
        im[rv] = 0.f;
    }
    for (int s = 1; s <= LOG2N; ++s) {
        int half = 1 << (s - 1);
        __syncthreads();
        for (int j = tid; j < NFFT/2; j += 256) {
            int pos = j & (half - 1);
            int i1 = ((j >> (s - 1)) << s) | pos;
            int i2 = i1 + half;
            float ang = -3.14159265358979f * (float)pos / (float)half;
            float wr, wi; __sincosf(ang, &wi, &wr);
            float xr = re[i2], xi = im[i2];
            float tr = wr*xr - wi*xi, ti = wr*xi + wi*xr;
            float ur = re[i1], ui = im[i1];
            re[i1] = ur + tr; im[i1] = ui + ti;
            re[i2] = ur - tr; im[i2] = ui - ti;
        }
    }
    __syncthreads();
    const float inv_n = 1.0f / (float)NFFT;
    for (int t = tid; t < NFFT; t += 256)
        kf[(size_t)d * NFFT + t] = make_float2(re[t]*inv_n, im[t]*inv_n);
}

// ---------------------------------------------------------------------------
// K4: per-(b,d) FFT conv: y = IDFT(V .* kf), out = (y + v*bias)*x2 in place
// ---------------------------------------------------------------------------
__global__ __launch_bounds__(256) void k_fftconv(
        const float* __restrict__ vbuf, const float2* __restrict__ kf,
        const float* __restrict__ fbias, float* __restrict__ x2y) {
    __shared__ float re[NFFT], im[NFFT];
    const int bd = blockIdx.x;
    const int d  = bd % DD;
    const int tid = threadIdx.x;
    const float* v = vbuf + (size_t)bd * LL;
    for (int t = tid; t < NFFT; t += 256) {
        int rv = brev13(t);
        re[rv] = (t < LL) ? v[t] : 0.f;
        im[rv] = 0.f;
    }
    // forward DIT
    for (int s = 1; s <= LOG2N; ++s) {
        int half = 1 << (s - 1);
        __syncthreads();
        for (int j = tid; j < NFFT/2; j += 256) {
            int pos = j & (half - 1);
            int i1 = ((j >> (s - 1)) << s) | pos;
            int i2 = i1 + half;
            float ang = -3.14159265358979f * (float)pos / (float)half;
            float wr, wi; __sincosf(ang, &wi, &wr);
            float xr = re[i2], xi = im[i2];
            float tr = wr*xr - wi*xi, ti = wr*xi + wi*xr;
            float ur = re[i1], ui = im[i1];
            re[i1] = ur + tr; im[i1] = ui + ti;
            re[i2] = ur - tr; im[i2] = ui - ti;
        }
    }
    __syncthreads();
    for (int t = tid; t < NFFT; t += 256) {
        float2 w = kf[(size_t)d * NFFT + t];
        float ar = re[t], ai = im[t];
        float pr = ar*w.x - ai*w.y;
        float pi = ar*w.y + ai*w.x;
        re[t] = pr; im[t] = -pi;
    }
    // forward DIF: natural order in, bit-reversed out
    for (int s = LOG2N; s >= 1; --s) {
        int half = 1 << (s - 1);
        __syncthreads();
        for (int j = tid; j < NFFT/2; j += 256) {
            int pos = j & (half - 1);
            int i1 = ((j >> (s - 1)) << s) | pos;
            int i2 = i1 + half;
            float ur = re[i1], ui = im[i1];
            float vr = re[i2], vi = im[i2];
            re[i1] = ur + vr; im[i1] = ui + vi;
            float dr = ur - vr, di = ui - vi;
            float ang = -3.14159265358979f * (float)pos / (float)half;
            float wr, wi; __sincosf(ang, &wi, &wr);
            re[i2] = wr*dr - wi*di;
            im[i2] = wr*di + wi*dr;
        }
    }
    __syncthreads();
    const float fb = fbias[d];
    float* x2p = x2y + (size_t)bd * LL;
    for (int t = tid; t < LL; t += 256) {
        float y = re[brev13(t)];            // Re(conj(Q)) == Re(Q)
        float val = (y + v[t] * fb) * x2p[t];
        x2p[t] = val;
    }
}

// ---------------------------------------------------------------------------
// K5: transpose-cast: yg (B,D,L) fp32 -> ygT (B,L,D) bf16, 64x64 LDS tile
// ---------------------------------------------------------------------------
__global__ __launch_bounds__(256) void k_transpose_cast(
        const float* __restrict__ yg, unsigned short* __restrict__ ygT) {
    __shared__ float t[64][65];
    const int b = blockIdx.z;
    const int d0 = blockIdx.y * 64;
    const int l0 = blockIdx.x * 64;
    for (int idx = threadIdx.x; idx < 4096; idx += 256) {
        int r = idx >> 6, c = idx & 63;       // r = d offset, c = l offset
        t[r][c] = yg[((size_t)(b * DD + d0 + r)) * LL + l0 + c];
    }
    __syncthreads();
    for (int idx = threadIdx.x; idx < 2048; idx += 256) {
        int r = idx >> 5, c = (idx & 31) * 2; // r = l offset, c = d offset (x2)
        unsigned int p = (unsigned int)f2b(t[c][r]) | ((unsigned int)f2b(t[c+1][r]) << 16);
        *(unsigned int*)&ygT[((size_t)(b * LL + l0 + r)) * DD + d0 + c] = p;
    }
}

// ---------------------------------------------------------------------------
extern "C" void kernel_launch(void* const* d_in, const int* in_sizes, int n_in,
                              void* d_out, int out_size, void* d_ws, size_t ws_size,
                              hipStream_t stream) {
    const float* u      = (const float*)d_in[0];
    const float* w_in   = (const float*)d_in[1];
    const float* b_in   = (const float*)d_in[2];
    const float* w_out  = (const float*)d_in[3];
    const float* b_out  = (const float*)d_in[4];
    const float* conv_w = (const float*)d_in[5];
    const float* conv_b = (const float*)d_in[6];
    const float* z      = (const float*)d_in[7];
    const float* fw1    = (const float*)d_in[8];
    const float* fb1    = (const float*)d_in[9];
    const float* fw2    = (const float*)d_in[10];
    const float* fb2    = (const float*)d_in[11];
    const float* fw3    = (const float*)d_in[12];
    const float* fb3    = (const float*)d_in[13];
    const float* fw4    = (const float*)d_in[14];
    const float* freq   = (const float*)d_in[15];
    const float* fbias  = (const float*)d_in[16];

    char* ws = (char*)d_ws;
    // Region X [0, 150994944): x fp32 (GEMM1 out, dead after shortconv), then:
    //   kf @ 0 (50331648 B), h3g @ 50331648 (262144 B),
    //   kt @ 50593792 (12582912 B; after k_fft_filter reused for w_out_bf),
    //   ygT @ 63176704 (25165824 B)
    // Region V [150994944, 201326592): vbuf fp32
    // Region Y [201326592, 251658240): x2y fp32; BEFORE shortconv holds
    //   u_bf @ 201326592 (25165824 B), w_in_bf @ 226492416 (3538944 B)
    float*  x        = (float*)(ws);
    float2* kf       = (float2*)(ws);
    float*  h3g      = (float*)(ws + 50331648);
    float*  kt       = (float*)(ws + 50593792);
    unsigned short* w_out_bf = (unsigned short*)(ws + 50593792);
    unsigned short* ygT      = (unsigned short*)(ws + 63176704);
    float*  vbuf     = (float*)(ws + 150994944);
    float*  x2y      = (float*)(ws + 201326592);
    unsigned short* u_bf     = (unsigned short*)(ws + 201326592);
    unsigned short* w_in_bf  = (unsigned short*)(ws + 226492416);

    // 0) cast u, w_in to bf16 (u: 3145728 float4s, w_in: 442368 float4s)
    k_cast_pair<<<(3145728 + 442368 + 255) / 256, 256, 0, stream>>>(
        u, 3145728ULL, w_in, 442368ULL, u_bf, w_in_bf);
    // 1) x = u @ w_in^T + b_in  (bf16 MFMA)
    k_gemm_mfma<<<dim3(TD/128, (BB*LL)/128), 256, 0, stream>>>(u_bf, w_in_bf, b_in, x, TD, DD);
    // 2) short conv + pre-gate; transpose to (B,D,L); overwrites u_bf region
    k_shortconv<<<dim3(LL/64, DD/32, BB), 256, 0, stream>>>(x, conv_w, conv_b, vbuf, x2y);
    // 3) filter: MLP -> k(d,l) -> FFT
    k_filter_mlp<<<LL/256, 256, 0, stream>>>(z, fw1, fb1, fw2, fb2, fw3, fb3, freq, h3g);
    k_filter_k<<<dim3(LL/256, DD), 256, 0, stream>>>(h3g, fw4, kt);
    k_fft_filter<<<DD, 256, 0, stream>>>(kt, kf);
    // 3b) cast w_out -> bf16 into the now-dead kt region (147456 float4s)
    k_cast_pair<<<(147456 + 255) / 256, 256, 0, stream>>>(
        w_out, 147456ULL, (const float*)0, 0ULL, w_out_bf, (unsigned short*)0);
    // 4) FFT long conv + bias + post-gate (in place over x2y)
    k_fftconv<<<BB*DD, 256, 0, stream>>>(vbuf, kf, fbias, x2y);
    // 5) transpose-cast gated y -> (B,L,D) bf16
    k_transpose_cast<<<dim3(LL/64, DD/64, BB), 256, 0, stream>>>(x2y, ygT);
    // 6) out = ygT @ w_out^T + b_out  (bf16 MFMA)
    k_gemm_mfma<<<dim3(DD/128, (BB*LL)/128), 256, 0, stream>>>(ygT, w_out_bf, b_out, (float*)d_out, DD, DD);
}

// Round 3
// 500.695 us; speedup vs baseline: 3.3105x; 1.8512x over previous
//
#include <hip/hip_runtime.h>

// Problem constants
#define BB 4
#define LL 4096
#define DD 768
#define TD 2304          // 3*D
#define NFFT 8192
#define LOG2N 13

// padded float2 LDS index: +1 slot per 16 to break power-of-2 bank strides
#define IDX(i) ((i) + ((i) >> 4))

__device__ __forceinline__ unsigned short f2b(float f) {
    unsigned u = __float_as_uint(f);
    unsigned r = (u + 0x7fffu + ((u >> 16) & 1u)) >> 16;
    return (unsigned short)r;
}

typedef __bf16 bf16x8 __attribute__((ext_vector_type(8)));
typedef float  f32x4  __attribute__((ext_vector_type(4)));

// ---------------------------------------------------------------------------
// Radix-4 DIF forward stage (M = 4q): natural->digit-reversed pipeline piece.
// u_j = (sum_t x_t W4^{tj}) * W_M^{mj}, stored at base + q*j.
// ---------------------------------------------------------------------------
__device__ __forceinline__ void r4_fwd_stage(float2* buf, int tid, int logq) {
    const int q = 1 << logq;
    const float ang = -6.283185307179586f / (float)(q << 2);
    __syncthreads();
#pragma unroll
    for (int r = 0; r < 8; ++r) {
        int bf = tid + (r << 8);
        int m = bf & (q - 1);
        int base = ((bf >> logq) << (logq + 2)) | m;
        float2 x0 = buf[IDX(base)];
        float2 x1 = buf[IDX(base + q)];
        float2 x2 = buf[IDX(base + 2 * q)];
        float2 x3 = buf[IDX(base + 3 * q)];
        float ar = x0.x + x2.x, ai = x0.y + x2.y;
        float br = x0.x - x2.x, bi = x0.y - x2.y;
        float cr = x1.x + x3.x, ci = x1.y + x3.y;
        float dr = x1.x - x3.x, di = x1.y - x3.y;
        float u0r = ar + cr, u0i = ai + ci;
        float u1r = br + di, u1i = bi - dr;     // b - i*d
        float u2r = ar - cr, u2i = ai - ci;
        float u3r = br - di, u3i = bi + dr;     // b + i*d
        float s, c1;
        __sincosf(ang * (float)m, &s, &c1);
        float w1r = c1, w1i = s;
        float w2r = w1r * w1r - w1i * w1i, w2i = 2.f * w1r * w1i;
        float w3r = w2r * w1r - w2i * w1i, w3i = w2r * w1i + w2i * w1r;
        buf[IDX(base)]         = make_float2(u0r, u0i);
        buf[IDX(base + q)]     = make_float2(u1r * w1r - u1i * w1i, u1r * w1i + u1i * w1r);
        buf[IDX(base + 2 * q)] = make_float2(u2r * w2r - u2i * w2i, u2r * w2i + u2i * w2r);
        buf[IDX(base + 3 * q)] = make_float2(u3r * w3r - u3i * w3i, u3r * w3i + u3i * w3r);
    }
}

// ---------------------------------------------------------------------------
// Radix-4 DIT inverse stage: exact transpose of r4_fwd_stage with conjugated
// twiddles. u_j = in[base+q*j]*conj(w^j); x_t = sum_j u_j * i^{tj}.
// Unnormalized (network contributes factor 4 per stage; total N folded in kf).
// ---------------------------------------------------------------------------
__device__ __forceinline__ void r4_inv_stage(float2* buf, int tid, int logq) {
    const int q = 1 << logq;
    const float ang = 6.283185307179586f / (float)(q << 2);
    __syncthreads();
#pragma unroll
    for (int r = 0; r < 8; ++r) {
        int bf = tid + (r << 8);
        int m = bf & (q - 1);
        int base = ((bf >> logq) << (logq + 2)) | m;
        float2 d0 = buf[IDX(base)];
        float2 d1 = buf[IDX(base + q)];
        float2 d2 = buf[IDX(base + 2 * q)];
        float2 d3 = buf[IDX(base + 3 * q)];
        float s, c1;
        __sincosf(ang * (float)m, &s, &c1);
        float w1r = c1, w1i = s;
        float w2r = w1r * w1r - w1i * w1i, w2i = 2.f * w1r * w1i;
        float w3r = w2r * w1r - w2i * w1i, w3i = w2r * w1i + w2i * w1r;
        float u0r = d0.x, u0i = d0.y;
        float u1r = d1.x * w1r - d1.y * w1i, u1i = d1.x * w1i + d1.y * w1r;
        float u2r = d2.x * w2r - d2.y * w2i, u2i = d2.x * w2i + d2.y * w2r;
        float u3r = d3.x * w3r - d3.y * w3i, u3i = d3.x * w3i + d3.y * w3r;
        float ar = u0r + u2r, ai = u0i + u2i;
        float br = u0r - u2r, bi = u0i - u2i;
        float cr = u1r + u3r, ci = u1i + u3i;
        float dr = u1r - u3r, di = u1i - u3i;
        buf[IDX(base)]         = make_float2(ar + cr, ai + ci);
        buf[IDX(base + q)]     = make_float2(br - di, bi + dr);   // b + i*d
        buf[IDX(base + 2 * q)] = make_float2(ar - cr, ai - ci);
        buf[IDX(base + 3 * q)] = make_float2(br + di, bi - dr);   // b - i*d
    }
}

// radix-2 stage (M=2, no twiddle) — self-transpose, used by both directions
__device__ __forceinline__ void r2_stage(float2* buf, int tid) {
    __syncthreads();
#pragma unroll
    for (int r = 0; r < 16; ++r) {
        int p = tid + (r << 8);
        int i0 = 2 * p;
        float2 d0 = buf[IDX(i0)];
        float2 d1 = buf[IDX(i0 + 1)];
        buf[IDX(i0)]     = make_float2(d0.x + d1.x, d0.y + d1.y);
        buf[IDX(i0 + 1)] = make_float2(d0.x - d1.x, d0.y - d1.y);
    }
}

// ---------------------------------------------------------------------------
// K0: fp32 -> bf16 cast (two sources fused), float4 granularity
// ---------------------------------------------------------------------------
__global__ __launch_bounds__(256) void k_cast_pair(
        const float* __restrict__ srcA, unsigned long long nA4,
        const float* __restrict__ srcB, unsigned long long nB4,
        unsigned short* __restrict__ dstA, unsigned short* __restrict__ dstB) {
    unsigned long long i = (unsigned long long)blockIdx.x * 256 + threadIdx.x;
    const float* s; unsigned short* d;
    if (i < nA4)            { s = srcA + i * 4;         d = dstA + i * 4; }
    else if (i < nA4 + nB4) { unsigned long long j = i - nA4; s = srcB + j * 4; d = dstB + j * 4; }
    else return;
    float4 v = *(const float4*)s;
    unsigned long long p = (unsigned long long)f2b(v.x)
                         | ((unsigned long long)f2b(v.y) << 16)
                         | ((unsigned long long)f2b(v.z) << 32)
                         | ((unsigned long long)f2b(v.w) << 48);
    *(unsigned long long*)d = p;
}

// ---------------------------------------------------------------------------
// K1: bf16 MFMA GEMM (NT): C[m][n] = sum_k A[m][k]*Bw[n][k] + bias[n]
// ---------------------------------------------------------------------------
__global__ __launch_bounds__(256) void k_gemm_mfma(
        const unsigned short* __restrict__ A, const unsigned short* __restrict__ Bw,
        const float* __restrict__ bias, float* __restrict__ C,
        int N, int K) {
    __shared__ unsigned char AsB[8192];
    __shared__ unsigned char BsB[8192];
    const int tid  = threadIdx.x;
    const int lane = tid & 63;
    const int w    = tid >> 6;
    const int wr   = w >> 1, wc = w & 1;
    const int m0 = blockIdx.y * 128, n0 = blockIdx.x * 128;
    f32x4 acc[4][4] = {};
    const int rowIn = lane >> 2;
    const int k16   = lane & 3;
    for (int k0 = 0; k0 < K; k0 += 32) {
#pragma unroll
        for (int c = 0; c < 2; ++c) {
            int chunk = w * 2 + c;
            int row = chunk * 16 + rowIn;
            const char* ga = (const char*)A  + (((size_t)(m0 + row) * K + k0) * 2) + k16 * 16;
            __builtin_amdgcn_global_load_lds(
                (const __attribute__((address_space(1))) void*)ga,
                (__attribute__((address_space(3))) void*)(AsB + chunk * 1024), 16, 0, 0);
            const char* gb = (const char*)Bw + (((size_t)(n0 + row) * K + k0) * 2) + k16 * 16;
            __builtin_amdgcn_global_load_lds(
                (const __attribute__((address_space(1))) void*)gb,
                (__attribute__((address_space(3))) void*)(BsB + chunk * 1024), 16, 0, 0);
        }
        __syncthreads();
        const int koff = (lane >> 4) * 16;
        const int rsel = lane & 15;
        bf16x8 af[4], bfr[4];
#pragma unroll
        for (int i = 0; i < 4; ++i) {
            af[i]  = *(const bf16x8*)(AsB + (wr * 64 + i * 16 + rsel) * 64 + koff);
            bfr[i] = *(const bf16x8*)(BsB + (wc * 64 + i * 16 + rsel) * 64 + koff);
        }
#pragma unroll
        for (int i = 0; i < 4; ++i)
#pragma unroll
            for (int j = 0; j < 4; ++j)
                acc[i][j] = __builtin_amdgcn_mfma_f32_16x16x32_bf16(af[i], bfr[j], acc[i][j], 0, 0, 0);
        __syncthreads();
    }
    const int cq = lane >> 4;
    const int cn = lane & 15;
#pragma unroll
    for (int j = 0; j < 4; ++j) {
        int col = n0 + wc * 64 + j * 16 + cn;
        float bv = bias[col];
#pragma unroll
        for (int i = 0; i < 4; ++i) {
            int rbase = m0 + wr * 64 + i * 16 + cq * 4;
#pragma unroll
            for (int r = 0; r < 4; ++r)
                C[(size_t)(rbase + r) * N + col] = acc[i][j][r] + bv;
        }
    }
}

// ---------------------------------------------------------------------------
// K2: depthwise short conv (k=3, causal lookback 2) + gating + transpose
// ---------------------------------------------------------------------------
__global__ __launch_bounds__(256) void k_shortconv(
        const float* __restrict__ x, const float* __restrict__ conv_w,
        const float* __restrict__ conv_b,
        float* __restrict__ vbuf, float* __restrict__ x2buf) {
    __shared__ float xs[3][32][66];
    const int l0 = blockIdx.x * 64;
    const int d0 = blockIdx.y * 32;
    const int b  = blockIdx.z;
    const int tid = threadIdx.x;
    for (int idx = tid; idx < 3 * 66 * 32; idx += 256) {
        int g  = idx / (66 * 32);
        int r  = idx % (66 * 32);
        int ll = r >> 5;
        int dd = r & 31;
        int gl = l0 - 2 + ll;
        float val = 0.f;
        if (gl >= 0) val = x[((size_t)(b * LL + gl)) * TD + g * DD + d0 + dd];
        xs[g][dd][ll] = val;
    }
    __syncthreads();
    const int tl  = tid & 63;
    const int tdq = tid >> 6;
    for (int dd = tdq; dd < 32; dd += 4) {
        int c0 = d0 + dd;
        const float* w0 = conv_w + (size_t)c0 * 3;
        const float* w1 = conv_w + (size_t)(DD + c0) * 3;
        const float* w2 = conv_w + (size_t)(2 * DD + c0) * 3;
        float x1v = w0[0]*xs[0][dd][tl] + w0[1]*xs[0][dd][tl+1] + w0[2]*xs[0][dd][tl+2] + conv_b[c0];
        float x2v = w1[0]*xs[1][dd][tl] + w1[1]*xs[1][dd][tl+1] + w1[2]*xs[1][dd][tl+2] + conv_b[DD + c0];
        float vv  = w2[0]*xs[2][dd][tl] + w2[1]*xs[2][dd][tl+1] + w2[2]*xs[2][dd][tl+2] + conv_b[2*DD + c0];
        size_t o = ((size_t)(b * DD + c0)) * LL + l0 + tl;
        vbuf[o]  = vv * x1v;
        x2buf[o] = x2v;
    }
}

// ---------------------------------------------------------------------------
// K3a: implicit filter MLP (3->16->16->16 with shared Sin), per position l
// ---------------------------------------------------------------------------
__global__ __launch_bounds__(256) void k_filter_mlp(
        const float* __restrict__ z,
        const float* __restrict__ fw1, const float* __restrict__ fb1,
        const float* __restrict__ fw2, const float* __restrict__ fb2,
        const float* __restrict__ fw3, const float* __restrict__ fb3,
        const float* __restrict__ freq, float* __restrict__ h3g) {
    int l = blockIdx.x * 256 + threadIdx.x;
    float z0 = z[l*3+0], z1 = z[l*3+1], z2 = z[l*3+2];
    float h1[16], h2[16];
#pragma unroll
    for (int j = 0; j < 16; ++j) {
        float a = z0*fw1[j*3+0] + z1*fw1[j*3+1] + z2*fw1[j*3+2] + fb1[j];
        h1[j] = sinf(freq[j] * a);
    }
#pragma unroll
    for (int j = 0; j < 16; ++j) {
        float a = fb2[j];
#pragma unroll
        for (int i = 0; i < 16; ++i) a += h1[i] * fw2[j*16+i];
        h2[j] = sinf(freq[j] * a);
    }
#pragma unroll
    for (int j = 0; j < 16; ++j) {
        float a = fb3[j];
#pragma unroll
        for (int i = 0; i < 16; ++i) a += h2[i] * fw3[j*16+i];
        h3g[l*16+j] = sinf(freq[j] * a);
    }
}

// ---------------------------------------------------------------------------
// K3b: k[d][l] = (h3[l] . fw4[d]) * exp(-t_l * |delta_d|)
// ---------------------------------------------------------------------------
__global__ __launch_bounds__(256) void k_filter_k(
        const float* __restrict__ h3g, const float* __restrict__ fw4,
        float* __restrict__ kt) {
    const int d = blockIdx.y;
    const int l = blockIdx.x * 256 + threadIdx.x;
    float acc = 0.f;
#pragma unroll
    for (int j = 0; j < 16; ++j) acc += h3g[l*16+j] * fw4[d*16+j];
    float t = (float)l / 4095.0f;
    const float min_d = -3.070113457325394f;   // ln(0.01)/1.5
    const float max_d = -15.35056728662697f;   // ln(0.01)/0.3
    float delta = min_d + (max_d - min_d) * ((float)d / 767.0f);
    acc *= expf(-t * fabsf(delta));
    kt[(size_t)d * LL + l] = acc;
}

// ---------------------------------------------------------------------------
// K3c: filter FFT via radix-4 DIF; kf stored in the SAME permuted order the
// conv kernel produces, scaled by 1/NFFT. One filter per block (im = 0).
// ---------------------------------------------------------------------------
__global__ __launch_bounds__(256) void k_fft_filter2(
        const float* __restrict__ kt, float2* __restrict__ kf) {
    __shared__ float2 buf[8704];
    const int d = blockIdx.x, tid = threadIdx.x;
    for (int t = tid; t < LL; t += 256) {
        buf[IDX(t)]      = make_float2(kt[(size_t)d * LL + t], 0.f);
        buf[IDX(t + LL)] = make_float2(0.f, 0.f);
    }
    r4_fwd_stage(buf, tid, 11);
    r4_fwd_stage(buf, tid, 9);
    r4_fwd_stage(buf, tid, 7);
    r4_fwd_stage(buf, tid, 5);
    r4_fwd_stage(buf, tid, 3);
    r4_fwd_stage(buf, tid, 1);
    r2_stage(buf, tid);
    __syncthreads();
    const float inv_n = 1.0f / (float)NFFT;
    for (int t = tid; t < NFFT; t += 256) {
        float2 zv = buf[IDX(t)];
        kf[(size_t)d * NFFT + t] = make_float2(zv.x * inv_n, zv.y * inv_n);
    }
}

// ---------------------------------------------------------------------------
// K4: packed FFT conv. Two real channels (b,d),(b+1,d) share one complex FFT
// (same kf row). Forward radix-4 DIF (natural->perm), pointwise in permuted
// domain, transposed-reverse radix-4 DIT back to natural. Epilogue applies
// bias + post-gate for both channels in place over x2y.
// ---------------------------------------------------------------------------
__global__ __launch_bounds__(256) void k_fftconv2(
        const float* __restrict__ vbuf, const float2* __restrict__ kf,
        const float* __restrict__ fbias, float* __restrict__ x2y) {
    __shared__ float2 buf[8704];
    const int p = blockIdx.x;           // 0..1535
    const int d = p % DD;
    const int bpair = p / DD;           // 0 or 1 -> batches (0,1) or (2,3)
    const size_t row1 = (size_t)(bpair * 2) * DD + d;
    const size_t row2 = row1 + DD;
    const float* v1 = vbuf + row1 * LL;
    const float* v2 = vbuf + row2 * LL;
    const int tid = threadIdx.x;
    for (int t = tid; t < LL; t += 256) {
        buf[IDX(t)]      = make_float2(v1[t], v2[t]);
        buf[IDX(t + LL)] = make_float2(0.f, 0.f);
    }
    // forward DIF: natural -> permuted
    r4_fwd_stage(buf, tid, 11);
    r4_fwd_stage(buf, tid, 9);
    r4_fwd_stage(buf, tid, 7);
    r4_fwd_stage(buf, tid, 5);
    r4_fwd_stage(buf, tid, 3);
    r4_fwd_stage(buf, tid, 1);
    r2_stage(buf, tid);
    __syncthreads();
    // pointwise multiply in permuted domain (kf stored in identical order)
    const float2* kd = kf + (size_t)d * NFFT;
    for (int t = tid; t < NFFT; t += 256) {
        float2 w = kd[t];
        float2 zv = buf[IDX(t)];
        buf[IDX(t)] = make_float2(zv.x * w.x - zv.y * w.y, zv.x * w.y + zv.y * w.x);
    }
    // inverse DIT: permuted -> natural (unnormalized; 1/N folded in kf)
    r2_stage(buf, tid);
    r4_inv_stage(buf, tid, 1);
    r4_inv_stage(buf, tid, 3);
    r4_inv_stage(buf, tid, 5);
    r4_inv_stage(buf, tid, 7);
    r4_inv_stage(buf, tid, 9);
    r4_inv_stage(buf, tid, 11);
    __syncthreads();
    const float fb = fbias[d];
    float* o1 = x2y + row1 * LL;
    float* o2 = x2y + row2 * LL;
    for (int t = tid; t < LL; t += 256) {
        float2 y = buf[IDX(t)];
        o1[t] = (y.x + v1[t] * fb) * o1[t];
        o2[t] = (y.y + v2[t] * fb) * o2[t];
    }
}

// ---------------------------------------------------------------------------
// K5: transpose-cast: yg (B,D,L) fp32 -> ygT (B,L,D) bf16, 64x64 LDS tile
// ---------------------------------------------------------------------------
__global__ __launch_bounds__(256) void k_transpose_cast(
        const float* __restrict__ yg, unsigned short* __restrict__ ygT) {
    __shared__ float t[64][65];
    const int b = blockIdx.z;
    const int d0 = blockIdx.y * 64;
    const int l0 = blockIdx.x * 64;
    for (int idx = threadIdx.x; idx < 4096; idx += 256) {
        int r = idx >> 6, c = idx & 63;
        t[r][c] = yg[((size_t)(b * DD + d0 + r)) * LL + l0 + c];
    }
    __syncthreads();
    for (int idx = threadIdx.x; idx < 2048; idx += 256) {
        int r = idx >> 5, c = (idx & 31) * 2;
        unsigned int p = (unsigned int)f2b(t[c][r]) | ((unsigned int)f2b(t[c+1][r]) << 16);
        *(unsigned int*)&ygT[((size_t)(b * LL + l0 + r)) * DD + d0 + c] = p;
    }
}

// ---------------------------------------------------------------------------
extern "C" void kernel_launch(void* const* d_in, const int* in_sizes, int n_in,
                              void* d_out, int out_size, void* d_ws, size_t ws_size,
                              hipStream_t stream) {
    const float* u      = (const float*)d_in[0];
    const float* w_in   = (const float*)d_in[1];
    const float* b_in   = (const float*)d_in[2];
    const float* w_out  = (const float*)d_in[3];
    const float* b_out  = (const float*)d_in[4];
    const float* conv_w = (const float*)d_in[5];
    const float* conv_b = (const float*)d_in[6];
    const float* z      = (const float*)d_in[7];
    const float* fw1    = (const float*)d_in[8];
    const float* fb1    = (const float*)d_in[9];
    const float* fw2    = (const float*)d_in[10];
    const float* fb2    = (const float*)d_in[11];
    const float* fw3    = (const float*)d_in[12];
    const float* fb3    = (const float*)d_in[13];
    const float* fw4    = (const float*)d_in[14];
    const float* freq   = (const float*)d_in[15];
    const float* fbias  = (const float*)d_in[16];

    char* ws = (char*)d_ws;
    float*  x        = (float*)(ws);
    float2* kf       = (float2*)(ws);
    float*  h3g      = (float*)(ws + 50331648);
    float*  kt       = (float*)(ws + 50593792);
    unsigned short* w_out_bf = (unsigned short*)(ws + 50593792);
    unsigned short* ygT      = (unsigned short*)(ws + 63176704);
    float*  vbuf     = (float*)(ws + 150994944);
    float*  x2y      = (float*)(ws + 201326592);
    unsigned short* u_bf     = (unsigned short*)(ws + 201326592);
    unsigned short* w_in_bf  = (unsigned short*)(ws + 226492416);

    // 0) cast u, w_in to bf16
    k_cast_pair<<<(3145728 + 442368 + 255) / 256, 256, 0, stream>>>(
        u, 3145728ULL, w_in, 442368ULL, u_bf, w_in_bf);
    // 1) x = u @ w_in^T + b_in  (bf16 MFMA)
    k_gemm_mfma<<<dim3(TD/128, (BB*LL)/128), 256, 0, stream>>>(u_bf, w_in_bf, b_in, x, TD, DD);
    // 2) short conv + pre-gate; transpose to (B,D,L)
    k_shortconv<<<dim3(LL/64, DD/32, BB), 256, 0, stream>>>(x, conv_w, conv_b, vbuf, x2y);
    // 3) filter: MLP -> k(d,l) -> FFT (permuted-order spectrum)
    k_filter_mlp<<<LL/256, 256, 0, stream>>>(z, fw1, fb1, fw2, fb2, fw3, fb3, freq, h3g);
    k_filter_k<<<dim3(LL/256, DD), 256, 0, stream>>>(h3g, fw4, kt);
    k_fft_filter2<<<DD, 256, 0, stream>>>(kt, kf);
    // 3b) cast w_out -> bf16 into the now-dead kt region
    k_cast_pair<<<(147456 + 255) / 256, 256, 0, stream>>>(
        w_out, 147456ULL, (const float*)0, 0ULL, w_out_bf, (unsigned short*)0);
    // 4) packed FFT long conv + bias + post-gate (in place over x2y)
    k_fftconv2<<<(BB/2)*DD, 256, 0, stream>>>(vbuf, kf, fbias, x2y);
    // 5) transpose-cast gated y -> (B,L,D) bf16
    k_transpose_cast<<<dim3(LL/64, DD/64, BB), 256, 0, stream>>>(x2y, ygT);
    // 6) out = ygT @ w_out^T + b_out  (bf16 MFMA)
    k_gemm_mfma<<<dim3(DD/128, (BB*LL)/128), 256, 0, stream>>>(ygT, w_out_bf, b_out, (float*)d_out, DD, DD);
}

// Round 4
// 449.355 us; speedup vs baseline: 3.6888x; 1.1143x over previous
//
#include <hip/hip_runtime.h>

// Problem constants
#define BB 4
#define LL 4096
#define DD 768
#define TD 2304          // 3*D
#define NFFT 8192
#define PI2 6.283185307179586f

__device__ __forceinline__ unsigned short f2b(float f) {
    unsigned u = __float_as_uint(f);
    unsigned r = (u + 0x7fffu + ((u >> 16) & 1u)) >> 16;
    return (unsigned short)r;
}

typedef __bf16 bf16x8 __attribute__((ext_vector_type(8)));
typedef float  f32x4  __attribute__((ext_vector_type(4)));

// ---------------------------------------------------------------------------
// Register FFT machinery. 8192 = 32(reg) x 16(reg) x 16(reg); two LDS
// transposes. All register DFTs natural-in/natural-out with constant
// twiddles; inverse = conjugated chain (unnormalized; 1/N folded into kf).
// ---------------------------------------------------------------------------
constexpr float TWC[16] = {
    1.f, 0.98078528f, 0.92387953f, 0.83146961f,
    0.70710678f, 0.55557023f, 0.38268343f, 0.19509032f,
    0.f, -0.19509032f, -0.38268343f, -0.55557023f,
    -0.70710678f, -0.83146961f, -0.92387953f, -0.98078528f};
constexpr float TWS[16] = {
    0.f, 0.19509032f, 0.38268343f, 0.55557023f,
    0.70710678f, 0.83146961f, 0.92387953f, 0.98078528f,
    1.f, 0.98078528f, 0.92387953f, 0.83146961f,
    0.70710678f, 0.55557023f, 0.38268343f, 0.19509032f};

// in-place natural-order DFT of size 2^LOGN over R; INV => conjugated (e^{+})
template<int LOGN, bool INV>
__device__ __forceinline__ void reg_fft(float2* R) {
    constexpr int N = 1 << LOGN;
#pragma unroll
    for (int i = 0; i < N; ++i) {
        int j = 0;
#pragma unroll
        for (int b = 0; b < LOGN; ++b) if (i & (1 << b)) j |= (1 << (LOGN - 1 - b));
        if (j > i) { float2 tt = R[i]; R[i] = R[j]; R[j] = tt; }
    }
#pragma unroll
    for (int s = 1; s <= LOGN; ++s) {
        const int hm = 1 << (s - 1);
        const int tsh = 5 - s;
#pragma unroll
        for (int g = 0; g < N; g += (hm << 1)) {
#pragma unroll
            for (int j2 = 0; j2 < hm; ++j2) {
                const float wr = TWC[j2 << tsh];
                const float wi = INV ? TWS[j2 << tsh] : -TWS[j2 << tsh];
                float2 u = R[g + j2];
                float2 v = R[g + j2 + hm];
                float vr = v.x * wr - v.y * wi;
                float vi = v.x * wi + v.y * wr;
                R[g + j2]      = make_float2(u.x + vr, u.y + vi);
                R[g + j2 + hm] = make_float2(u.x - vr, u.y - vi);
            }
        }
    }
}

// R[k] *= e^{i * ang * k}, k = 0..NN-1 (incremental complex power)
template<int NN>
__device__ __forceinline__ void ramp_mul(float2* R, float ang) {
    float s0, c0; __sincosf(ang, &s0, &c0);
    float wr = c0, wi = s0;
#pragma unroll
    for (int k = 1; k < NN; ++k) {
        float xr = R[k].x, xi = R[k].y;
        R[k] = make_float2(xr * wr - xi * wi, xr * wi + xi * wr);
        float nr = wr * c0 - wi * s0;
        float ni = wr * s0 + wi * c0;
        wr = nr; wi = ni;
    }
}

// LDS transpose addressing (injective, bank-spread; float2 units)
#define A1(t, k2) ((k2) * 288 + (t) + ((t) >> 3))
#define A2(k2, p, r) ((k2) * 272 + (r) * 17 + (p))
#define FFT_LDS 9216

// Forward: in: R[j] = x[t + 256*j] (natural); out: R[h*16 + r2] =
// X[(2*k2c+h) + 32*rr + 512*r2] where k2c = t>>4, rr = t&15 (engine order).
__device__ __forceinline__ void eng_fwd(float2* buf, float2* R, int t) {
    reg_fft<5, false>(R);
    ramp_mul<32>(R, -PI2 * (float)t / 8192.0f);
    __syncthreads();
#pragma unroll
    for (int k2 = 0; k2 < 32; ++k2) buf[A1(t, k2)] = R[k2];
    __syncthreads();
    const int p = t & 15, c2 = (t >> 4) << 1;
#pragma unroll
    for (int q = 0; q < 16; ++q) {
        R[q]      = buf[A1(p + 16 * q, c2)];
        R[16 + q] = buf[A1(p + 16 * q, c2 + 1)];
    }
    reg_fft<4, false>(R);
    reg_fft<4, false>(R + 16);
    float a2 = -PI2 * (float)p / 256.0f;
    ramp_mul<16>(R, a2);
    ramp_mul<16>(R + 16, a2);
    __syncthreads();
#pragma unroll
    for (int r = 0; r < 16; ++r) {
        buf[A2(c2, p, r)]     = R[r];
        buf[A2(c2 + 1, p, r)] = R[16 + r];
    }
    __syncthreads();
    const int rr = p;
#pragma unroll
    for (int pp = 0; pp < 16; ++pp) {
        R[pp]      = buf[A2(c2, pp, rr)];
        R[16 + pp] = buf[A2(c2 + 1, pp, rr)];
    }
    reg_fft<4, false>(R);
    reg_fft<4, false>(R + 16);
}

// Inverse (unnormalized, x8192): exact conjugated mirror of eng_fwd.
__device__ __forceinline__ void eng_inv(float2* buf, float2* R, int t) {
    const int p = t & 15, c2 = (t >> 4) << 1, rr = p;
    reg_fft<4, true>(R);
    reg_fft<4, true>(R + 16);
    __syncthreads();
#pragma unroll
    for (int pp = 0; pp < 16; ++pp) {
        buf[A2(c2, pp, rr)]     = R[pp];
        buf[A2(c2 + 1, pp, rr)] = R[16 + pp];
    }
    __syncthreads();
#pragma unroll
    for (int r = 0; r < 16; ++r) {
        R[r]      = buf[A2(c2, p, r)];
        R[16 + r] = buf[A2(c2 + 1, p, r)];
    }
    float a2 = PI2 * (float)p / 256.0f;
    ramp_mul<16>(R, a2);
    ramp_mul<16>(R + 16, a2);
    reg_fft<4, true>(R);
    reg_fft<4, true>(R + 16);
    __syncthreads();
#pragma unroll
    for (int q = 0; q < 16; ++q) {
        buf[A1(p + 16 * q, c2)]     = R[q];
        buf[A1(p + 16 * q, c2 + 1)] = R[16 + q];
    }
    __syncthreads();
#pragma unroll
    for (int k2 = 0; k2 < 32; ++k2) R[k2] = buf[A1(t, k2)];
    ramp_mul<32>(R, PI2 * (float)t / 8192.0f);
    reg_fft<5, true>(R);
}

// ---------------------------------------------------------------------------
// K0: fp32 -> bf16 cast (two sources fused), float4 granularity
// ---------------------------------------------------------------------------
__global__ __launch_bounds__(256) void k_cast_pair(
        const float* __restrict__ srcA, unsigned long long nA4,
        const float* __restrict__ srcB, unsigned long long nB4,
        unsigned short* __restrict__ dstA, unsigned short* __restrict__ dstB) {
    unsigned long long i = (unsigned long long)blockIdx.x * 256 + threadIdx.x;
    const float* s; unsigned short* d;
    if (i < nA4)            { s = srcA + i * 4;         d = dstA + i * 4; }
    else if (i < nA4 + nB4) { unsigned long long j = i - nA4; s = srcB + j * 4; d = dstB + j * 4; }
    else return;
    float4 v = *(const float4*)s;
    unsigned long long p = (unsigned long long)f2b(v.x)
                         | ((unsigned long long)f2b(v.y) << 16)
                         | ((unsigned long long)f2b(v.z) << 32)
                         | ((unsigned long long)f2b(v.w) << 48);
    *(unsigned long long*)d = p;
}

// ---------------------------------------------------------------------------
// K1: bf16 MFMA GEMM (NT): C[m][n] = sum_k A[m][k]*Bw[n][k] + bias[n]
// ---------------------------------------------------------------------------
__global__ __launch_bounds__(256) void k_gemm_mfma(
        const unsigned short* __restrict__ A, const unsigned short* __restrict__ Bw,
        const float* __restrict__ bias, float* __restrict__ C,
        int N, int K) {
    __shared__ unsigned char AsB[8192];
    __shared__ unsigned char BsB[8192];
    const int tid  = threadIdx.x;
    const int lane = tid & 63;
    const int w    = tid >> 6;
    const int wr   = w >> 1, wc = w & 1;
    const int m0 = blockIdx.y * 128, n0 = blockIdx.x * 128;
    f32x4 acc[4][4] = {};
    const int rowIn = lane >> 2;
    const int k16   = lane & 3;
    for (int k0 = 0; k0 < K; k0 += 32) {
#pragma unroll
        for (int c = 0; c < 2; ++c) {
            int chunk = w * 2 + c;
            int row = chunk * 16 + rowIn;
            const char* ga = (const char*)A  + (((size_t)(m0 + row) * K + k0) * 2) + k16 * 16;
            __builtin_amdgcn_global_load_lds(
                (const __attribute__((address_space(1))) void*)ga,
                (__attribute__((address_space(3))) void*)(AsB + chunk * 1024), 16, 0, 0);
            const char* gb = (const char*)Bw + (((size_t)(n0 + row) * K + k0) * 2) + k16 * 16;
            __builtin_amdgcn_global_load_lds(
                (const __attribute__((address_space(1))) void*)gb,
                (__attribute__((address_space(3))) void*)(BsB + chunk * 1024), 16, 0, 0);
        }
        __syncthreads();
        const int koff = (lane >> 4) * 16;
        const int rsel = lane & 15;
        bf16x8 af[4], bfr[4];
#pragma unroll
        for (int i = 0; i < 4; ++i) {
            af[i]  = *(const bf16x8*)(AsB + (wr * 64 + i * 16 + rsel) * 64 + koff);
            bfr[i] = *(const bf16x8*)(BsB + (wc * 64 + i * 16 + rsel) * 64 + koff);
        }
#pragma unroll
        for (int i = 0; i < 4; ++i)
#pragma unroll
            for (int j = 0; j < 4; ++j)
                acc[i][j] = __builtin_amdgcn_mfma_f32_16x16x32_bf16(af[i], bfr[j], acc[i][j], 0, 0, 0);
        __syncthreads();
    }
    const int cq = lane >> 4;
    const int cn = lane & 15;
#pragma unroll
    for (int j = 0; j < 4; ++j) {
        int col = n0 + wc * 64 + j * 16 + cn;
        float bv = bias[col];
#pragma unroll
        for (int i = 0; i < 4; ++i) {
            int rbase = m0 + wr * 64 + i * 16 + cq * 4;
#pragma unroll
            for (int r = 0; r < 4; ++r)
                C[(size_t)(rbase + r) * N + col] = acc[i][j][r] + bv;
        }
    }
}

// ---------------------------------------------------------------------------
// K2: depthwise short conv (k=3, causal lookback 2) + gating + transpose
// ---------------------------------------------------------------------------
__global__ __launch_bounds__(256) void k_shortconv(
        const float* __restrict__ x, const float* __restrict__ conv_w,
        const float* __restrict__ conv_b,
        float* __restrict__ vbuf, float* __restrict__ x2buf) {
    __shared__ float xs[3][32][66];
    const int l0 = blockIdx.x * 64;
    const int d0 = blockIdx.y * 32;
    const int b  = blockIdx.z;
    const int tid = threadIdx.x;
    for (int idx = tid; idx < 3 * 66 * 32; idx += 256) {
        int g  = idx / (66 * 32);
        int r  = idx % (66 * 32);
        int ll = r >> 5;
        int dd = r & 31;
        int gl = l0 - 2 + ll;
        float val = 0.f;
        if (gl >= 0) val = x[((size_t)(b * LL + gl)) * TD + g * DD + d0 + dd];
        xs[g][dd][ll] = val;
    }
    __syncthreads();
    const int tl  = tid & 63;
    const int tdq = tid >> 6;
    for (int dd = tdq; dd < 32; dd += 4) {
        int c0 = d0 + dd;
        const float* w0 = conv_w + (size_t)c0 * 3;
        const float* w1 = conv_w + (size_t)(DD + c0) * 3;
        const float* w2 = conv_w + (size_t)(2 * DD + c0) * 3;
        float x1v = w0[0]*xs[0][dd][tl] + w0[1]*xs[0][dd][tl+1] + w0[2]*xs[0][dd][tl+2] + conv_b[c0];
        float x2v = w1[0]*xs[1][dd][tl] + w1[1]*xs[1][dd][tl+1] + w1[2]*xs[1][dd][tl+2] + conv_b[DD + c0];
        float vv  = w2[0]*xs[2][dd][tl] + w2[1]*xs[2][dd][tl+1] + w2[2]*xs[2][dd][tl+2] + conv_b[2*DD + c0];
        size_t o = ((size_t)(b * DD + c0)) * LL + l0 + tl;
        vbuf[o]  = vv * x1v;
        x2buf[o] = x2v;
    }
}

// ---------------------------------------------------------------------------
// K3a: implicit filter MLP; output TRANSPOSED h3g[16][LL] for coalesced reads
// ---------------------------------------------------------------------------
__global__ __launch_bounds__(256) void k_filter_mlp(
        const float* __restrict__ z,
        const float* __restrict__ fw1, const float* __restrict__ fb1,
        const float* __restrict__ fw2, const float* __restrict__ fb2,
        const float* __restrict__ fw3, const float* __restrict__ fb3,
        const float* __restrict__ freq, float* __restrict__ h3g) {
    int l = blockIdx.x * 256 + threadIdx.x;
    float z0 = z[l*3+0], z1 = z[l*3+1], z2 = z[l*3+2];
    float h1[16], h2[16];
#pragma unroll
    for (int j = 0; j < 16; ++j) {
        float a = z0*fw1[j*3+0] + z1*fw1[j*3+1] + z2*fw1[j*3+2] + fb1[j];
        h1[j] = sinf(freq[j] * a);
    }
#pragma unroll
    for (int j = 0; j < 16; ++j) {
        float a = fb2[j];
#pragma unroll
        for (int i = 0; i < 16; ++i) a += h1[i] * fw2[j*16+i];
        h2[j] = sinf(freq[j] * a);
    }
#pragma unroll
    for (int j = 0; j < 16; ++j) {
        float a = fb3[j];
#pragma unroll
        for (int i = 0; i < 16; ++i) a += h2[i] * fw3[j*16+i];
        h3g[j * LL + l] = sinf(freq[j] * a);
    }
}

// ---------------------------------------------------------------------------
// K3b: fused filter construction + forward FFT. kf stored in engine order
// (e = i*256 + t), scaled by 1/NFFT, with filter_bias folded in (spectrum of
// bias*delta = constant bias at every bin).
// ---------------------------------------------------------------------------
__global__ __launch_bounds__(256) void k_filter_fft(
        const float* __restrict__ h3g, const float* __restrict__ fw4,
        const float* __restrict__ fbias, float2* __restrict__ kf) {
    __shared__ float2 buf[FFT_LDS];
    const int d = blockIdx.x, t = threadIdx.x;
    float w4[16];
#pragma unroll
    for (int i = 0; i < 16; ++i) w4[i] = fw4[d * 16 + i];
    const float min_d = 3.070113457325394f;    // |ln(0.01)/1.5|
    const float max_d = 15.35056728662697f;    // |ln(0.01)/0.3|
    const float ad = min_d + (max_d - min_d) * ((float)d / 767.0f);
    float2 R[32];
#pragma unroll
    for (int j = 0; j < 16; ++j) {
        int l = t + 256 * j;
        float acc = 0.f;
#pragma unroll
        for (int i = 0; i < 16; ++i) acc += h3g[i * LL + l] * w4[i];
        acc *= __expf(-((float)l / 4095.0f) * ad);
        R[j] = make_float2(acc, 0.f);
        R[16 + j] = make_float2(0.f, 0.f);
    }
    eng_fwd(buf, R, t);
    const float fb = fbias[d];
    const float inv_n = 1.0f / (float)NFFT;
    float2* kd = kf + (size_t)d * NFFT;
#pragma unroll
    for (int i = 0; i < 32; ++i)
        kd[i * 256 + t] = make_float2((R[i].x + fb) * inv_n, R[i].y * inv_n);
}

// ---------------------------------------------------------------------------
// K4: packed register-FFT conv. Channels (b,d),(b+1,d) in re/im. Bias folded
// into kf. Epilogue post-gates in place over x2y.
// ---------------------------------------------------------------------------
__global__ __launch_bounds__(256) void k_fftconv3(
        const float* __restrict__ vbuf, const float2* __restrict__ kf,
        float* __restrict__ x2y) {
    __shared__ float2 buf[FFT_LDS];
    const int bp = blockIdx.x;           // 0..1535
    const int d = bp % DD;
    const int bpair = bp / DD;
    const size_t row1 = (size_t)(bpair * 2) * DD + d;
    const size_t row2 = row1 + DD;
    const float* v1 = vbuf + row1 * LL;
    const float* v2 = vbuf + row2 * LL;
    const int t = threadIdx.x;
    float2 R[32];
#pragma unroll
    for (int j = 0; j < 16; ++j) {
        int idx = t + 256 * j;
        R[j] = make_float2(v1[idx], v2[idx]);
        R[16 + j] = make_float2(0.f, 0.f);
    }
    eng_fwd(buf, R, t);
    const float2* kd = kf + (size_t)d * NFFT;
#pragma unroll
    for (int i = 0; i < 32; ++i) {
        float2 w = kd[i * 256 + t];
        float2 zv = R[i];
        R[i] = make_float2(zv.x * w.x - zv.y * w.y, zv.x * w.y + zv.y * w.x);
    }
    eng_inv(buf, R, t);
    float* o1 = x2y + row1 * LL;
    float* o2 = x2y + row2 * LL;
#pragma unroll
    for (int j = 0; j < 16; ++j) {
        int idx = t + 256 * j;
        o1[idx] = R[j].x * o1[idx];
        o2[idx] = R[j].y * o2[idx];
    }
}

// ---------------------------------------------------------------------------
// K5: transpose-cast: yg (B,D,L) fp32 -> ygT (B,L,D) bf16, 64x64 LDS tile
// ---------------------------------------------------------------------------
__global__ __launch_bounds__(256) void k_transpose_cast(
        const float* __restrict__ yg, unsigned short* __restrict__ ygT) {
    __shared__ float t[64][65];
    const int b = blockIdx.z;
    const int d0 = blockIdx.y * 64;
    const int l0 = blockIdx.x * 64;
    for (int idx = threadIdx.x; idx < 4096; idx += 256) {
        int r = idx >> 6, c = idx & 63;
        t[r][c] = yg[((size_t)(b * DD + d0 + r)) * LL + l0 + c];
    }
    __syncthreads();
    for (int idx = threadIdx.x; idx < 2048; idx += 256) {
        int r = idx >> 5, c = (idx & 31) * 2;
        unsigned int p = (unsigned int)f2b(t[c][r]) | ((unsigned int)f2b(t[c+1][r]) << 16);
        *(unsigned int*)&ygT[((size_t)(b * LL + l0 + r)) * DD + d0 + c] = p;
    }
}

// ---------------------------------------------------------------------------
extern "C" void kernel_launch(void* const* d_in, const int* in_sizes, int n_in,
                              void* d_out, int out_size, void* d_ws, size_t ws_size,
                              hipStream_t stream) {
    const float* u      = (const float*)d_in[0];
    const float* w_in   = (const float*)d_in[1];
    const float* b_in   = (const float*)d_in[2];
    const float* w_out  = (const float*)d_in[3];
    const float* b_out  = (const float*)d_in[4];
    const float* conv_w = (const float*)d_in[5];
    const float* conv_b = (const float*)d_in[6];
    const float* z      = (const float*)d_in[7];
    const float* fw1    = (const float*)d_in[8];
    const float* fb1    = (const float*)d_in[9];
    const float* fw2    = (const float*)d_in[10];
    const float* fb2    = (const float*)d_in[11];
    const float* fw3    = (const float*)d_in[12];
    const float* fb3    = (const float*)d_in[13];
    const float* fw4    = (const float*)d_in[14];
    const float* freq   = (const float*)d_in[15];
    const float* fbias  = (const float*)d_in[16];

    char* ws = (char*)d_ws;
    // Region X [0, 150994944): x fp32 (GEMM1 out, dead after shortconv), then:
    //   kf @ 0 (50331648 B), h3g @ 50331648 (262144 B),
    //   w_out_bf @ 50593792 (3538944 B), ygT @ 63176704 (25165824 B)
    // Region V [150994944, 201326592): vbuf fp32
    // Region Y [201326592, 251658240): x2y fp32; BEFORE shortconv holds
    //   u_bf @ 201326592, w_in_bf @ 226492416
    float*  x        = (float*)(ws);
    float2* kf       = (float2*)(ws);
    float*  h3g      = (float*)(ws + 50331648);
    unsigned short* w_out_bf = (unsigned short*)(ws + 50593792);
    unsigned short* ygT      = (unsigned short*)(ws + 63176704);
    float*  vbuf     = (float*)(ws + 150994944);
    float*  x2y      = (float*)(ws + 201326592);
    unsigned short* u_bf     = (unsigned short*)(ws + 201326592);
    unsigned short* w_in_bf  = (unsigned short*)(ws + 226492416);

    // 0) cast u, w_in to bf16
    k_cast_pair<<<(3145728 + 442368 + 255) / 256, 256, 0, stream>>>(
        u, 3145728ULL, w_in, 442368ULL, u_bf, w_in_bf);
    // 1) x = u @ w_in^T + b_in  (bf16 MFMA)
    k_gemm_mfma<<<dim3(TD/128, (BB*LL)/128), 256, 0, stream>>>(u_bf, w_in_bf, b_in, x, TD, DD);
    // 2) short conv + pre-gate; transpose to (B,D,L)
    k_shortconv<<<dim3(LL/64, DD/32, BB), 256, 0, stream>>>(x, conv_w, conv_b, vbuf, x2y);
    // 3) filter: MLP -> fused (modulated k + FFT), engine-order spectrum
    k_filter_mlp<<<LL/256, 256, 0, stream>>>(z, fw1, fb1, fw2, fb2, fw3, fb3, freq, h3g);
    k_filter_fft<<<DD, 256, 0, stream>>>(h3g, fw4, fbias, kf);
    // 3b) cast w_out -> bf16
    k_cast_pair<<<(147456 + 255) / 256, 256, 0, stream>>>(
        w_out, 147456ULL, (const float*)0, 0ULL, w_out_bf, (unsigned short*)0);
    // 4) packed register-FFT long conv + post-gate (in place over x2y)
    k_fftconv3<<<(BB/2)*DD, 256, 0, stream>>>(vbuf, kf, x2y);
    // 5) transpose-cast gated y -> (B,L,D) bf16
    k_transpose_cast<<<dim3(LL/64, DD/64, BB), 256, 0, stream>>>(x2y, ygT);
    // 6) out = ygT @ w_out^T + b_out  (bf16 MFMA)
    k_gemm_mfma<<<dim3(DD/128, (BB*LL)/128), 256, 0, stream>>>(ygT, w_out_bf, b_out, (float*)d_out, DD, DD);
}

// Round 5
// 435.242 us; speedup vs baseline: 3.8084x; 1.0324x over previous
//
#include <hip/hip_runtime.h>

// Problem constants
#define BB 4
#define LL 4096
#define DD 768
#define TD 2304          // 3*D
#define NFFT 8192
#define PI2 6.283185307179586f

__device__ __forceinline__ unsigned short f2b(float f) {
    unsigned u = __float_as_uint(f);
    unsigned r = (u + 0x7fffu + ((u >> 16) & 1u)) >> 16;
    return (unsigned short)r;
}
__device__ __forceinline__ float b2f(unsigned short h) {
    return __uint_as_float((unsigned)h << 16);
}

typedef __bf16 bf16x8 __attribute__((ext_vector_type(8)));
typedef float  f32x4  __attribute__((ext_vector_type(4)));

// ---------------------------------------------------------------------------
// Register FFT machinery. 8192 = 32(reg) x 16(reg) x 16(reg); two LDS
// transposes. Natural-order register DFTs with constant twiddles; inverse =
// conjugated chain (unnormalized; 1/N folded into kf).
// ---------------------------------------------------------------------------
constexpr float TWC[16] = {
    1.f, 0.98078528f, 0.92387953f, 0.83146961f,
    0.70710678f, 0.55557023f, 0.38268343f, 0.19509032f,
    0.f, -0.19509032f, -0.38268343f, -0.55557023f,
    -0.70710678f, -0.83146961f, -0.92387953f, -0.98078528f};
constexpr float TWS[16] = {
    0.f, 0.19509032f, 0.38268343f, 0.55557023f,
    0.70710678f, 0.83146961f, 0.92387953f, 0.98078528f,
    1.f, 0.98078528f, 0.92387953f, 0.83146961f,
    0.70710678f, 0.55557023f, 0.38268343f, 0.19509032f};

template<int LOGN, bool INV>
__device__ __forceinline__ void reg_fft(float2* R) {
    constexpr int N = 1 << LOGN;
#pragma unroll
    for (int i = 0; i < N; ++i) {
        int j = 0;
#pragma unroll
        for (int b = 0; b < LOGN; ++b) if (i & (1 << b)) j |= (1 << (LOGN - 1 - b));
        if (j > i) { float2 tt = R[i]; R[i] = R[j]; R[j] = tt; }
    }
#pragma unroll
    for (int s = 1; s <= LOGN; ++s) {
        const int hm = 1 << (s - 1);
        const int tsh = 5 - s;
#pragma unroll
        for (int g = 0; g < N; g += (hm << 1)) {
#pragma unroll
            for (int j2 = 0; j2 < hm; ++j2) {
                const float wr = TWC[j2 << tsh];
                const float wi = INV ? TWS[j2 << tsh] : -TWS[j2 << tsh];
                float2 u = R[g + j2];
                float2 v = R[g + j2 + hm];
                float vr = v.x * wr - v.y * wi;
                float vi = v.x * wi + v.y * wr;
                R[g + j2]      = make_float2(u.x + vr, u.y + vi);
                R[g + j2 + hm] = make_float2(u.x - vr, u.y - vi);
            }
        }
    }
}

template<int NN>
__device__ __forceinline__ void ramp_mul(float2* R, float ang) {
    float s0, c0; __sincosf(ang, &s0, &c0);
    float wr = c0, wi = s0;
#pragma unroll
    for (int k = 1; k < NN; ++k) {
        float xr = R[k].x, xi = R[k].y;
        R[k] = make_float2(xr * wr - xi * wi, xr * wi + xi * wr);
        float nr = wr * c0 - wi * s0;
        float ni = wr * s0 + wi * c0;
        wr = nr; wi = ni;
    }
}

#define A1(t, k2) ((k2) * 288 + (t) + ((t) >> 3))
#define A2(k2, p, r) ((k2) * 272 + (r) * 17 + (p))
#define FFT_LDS 9216

__device__ __forceinline__ void eng_fwd(float2* buf, float2* R, int t) {
    reg_fft<5, false>(R);
    ramp_mul<32>(R, -PI2 * (float)t / 8192.0f);
    __syncthreads();
#pragma unroll
    for (int k2 = 0; k2 < 32; ++k2) buf[A1(t, k2)] = R[k2];
    __syncthreads();
    const int p = t & 15, c2 = (t >> 4) << 1;
#pragma unroll
    for (int q = 0; q < 16; ++q) {
        R[q]      = buf[A1(p + 16 * q, c2)];
        R[16 + q] = buf[A1(p + 16 * q, c2 + 1)];
    }
    reg_fft<4, false>(R);
    reg_fft<4, false>(R + 16);
    float a2 = -PI2 * (float)p / 256.0f;
    ramp_mul<16>(R, a2);
    ramp_mul<16>(R + 16, a2);
    __syncthreads();
#pragma unroll
    for (int r = 0; r < 16; ++r) {
        buf[A2(c2, p, r)]     = R[r];
        buf[A2(c2 + 1, p, r)] = R[16 + r];
    }
    __syncthreads();
    const int rr = p;
#pragma unroll
    for (int pp = 0; pp < 16; ++pp) {
        R[pp]      = buf[A2(c2, pp, rr)];
        R[16 + pp] = buf[A2(c2 + 1, pp, rr)];
    }
    reg_fft<4, false>(R);
    reg_fft<4, false>(R + 16);
}

__device__ __forceinline__ void eng_inv(float2* buf, float2* R, int t) {
    const int p = t & 15, c2 = (t >> 4) << 1, rr = p;
    reg_fft<4, true>(R);
    reg_fft<4, true>(R + 16);
    __syncthreads();
#pragma unroll
    for (int pp = 0; pp < 16; ++pp) {
        buf[A2(c2, pp, rr)]     = R[pp];
        buf[A2(c2 + 1, pp, rr)] = R[16 + pp];
    }
    __syncthreads();
#pragma unroll
    for (int r = 0; r < 16; ++r) {
        R[r]      = buf[A2(c2, p, r)];
        R[16 + r] = buf[A2(c2 + 1, p, r)];
    }
    float a2 = PI2 * (float)p / 256.0f;
    ramp_mul<16>(R, a2);
    ramp_mul<16>(R + 16, a2);
    reg_fft<4, true>(R);
    reg_fft<4, true>(R + 16);
    __syncthreads();
#pragma unroll
    for (int q = 0; q < 16; ++q) {
        buf[A1(p + 16 * q, c2)]     = R[q];
        buf[A1(p + 16 * q, c2 + 1)] = R[16 + q];
    }
    __syncthreads();
#pragma unroll
    for (int k2 = 0; k2 < 32; ++k2) R[k2] = buf[A1(t, k2)];
    ramp_mul<32>(R, PI2 * (float)t / 8192.0f);
    reg_fft<5, true>(R);
}

// ---------------------------------------------------------------------------
// K0: fp32 -> bf16 cast (two sources fused), float4 granularity
// ---------------------------------------------------------------------------
__global__ __launch_bounds__(256) void k_cast_pair(
        const float* __restrict__ srcA, unsigned long long nA4,
        const float* __restrict__ srcB, unsigned long long nB4,
        unsigned short* __restrict__ dstA, unsigned short* __restrict__ dstB) {
    unsigned long long i = (unsigned long long)blockIdx.x * 256 + threadIdx.x;
    const float* s; unsigned short* d;
    if (i < nA4)            { s = srcA + i * 4;         d = dstA + i * 4; }
    else if (i < nA4 + nB4) { unsigned long long j = i - nA4; s = srcB + j * 4; d = dstB + j * 4; }
    else return;
    float4 v = *(const float4*)s;
    unsigned long long p = (unsigned long long)f2b(v.x)
                         | ((unsigned long long)f2b(v.y) << 16)
                         | ((unsigned long long)f2b(v.z) << 32)
                         | ((unsigned long long)f2b(v.w) << 48);
    *(unsigned long long*)d = p;
}

// ---------------------------------------------------------------------------
// K1a: bf16 MFMA GEMM (NT), bf16 OUTPUT: x = A@Bw^T + bias, stored bf16.
// ---------------------------------------------------------------------------
__global__ __launch_bounds__(256) void k_gemm_mfma_b16(
        const unsigned short* __restrict__ A, const unsigned short* __restrict__ Bw,
        const float* __restrict__ bias, unsigned short* __restrict__ C,
        int N, int K) {
    __shared__ unsigned char AsB[8192];
    __shared__ unsigned char BsB[8192];
    const int tid  = threadIdx.x;
    const int lane = tid & 63;
    const int w    = tid >> 6;
    const int wr   = w >> 1, wc = w & 1;
    const int m0 = blockIdx.y * 128, n0 = blockIdx.x * 128;
    f32x4 acc[4][4] = {};
    const int rowIn = lane >> 2;
    const int k16   = lane & 3;
    for (int k0 = 0; k0 < K; k0 += 32) {
#pragma unroll
        for (int c = 0; c < 2; ++c) {
            int chunk = w * 2 + c;
            int row = chunk * 16 + rowIn;
            const char* ga = (const char*)A  + (((size_t)(m0 + row) * K + k0) * 2) + k16 * 16;
            __builtin_amdgcn_global_load_lds(
                (const __attribute__((address_space(1))) void*)ga,
                (__attribute__((address_space(3))) void*)(AsB + chunk * 1024), 16, 0, 0);
            const char* gb = (const char*)Bw + (((size_t)(n0 + row) * K + k0) * 2) + k16 * 16;
            __builtin_amdgcn_global_load_lds(
                (const __attribute__((address_space(1))) void*)gb,
                (__attribute__((address_space(3))) void*)(BsB + chunk * 1024), 16, 0, 0);
        }
        __syncthreads();
        const int koff = (lane >> 4) * 16;
        const int rsel = lane & 15;
        bf16x8 af[4], bfr[4];
#pragma unroll
        for (int i = 0; i < 4; ++i) {
            af[i]  = *(const bf16x8*)(AsB + (wr * 64 + i * 16 + rsel) * 64 + koff);
            bfr[i] = *(const bf16x8*)(BsB + (wc * 64 + i * 16 + rsel) * 64 + koff);
        }
#pragma unroll
        for (int i = 0; i < 4; ++i)
#pragma unroll
            for (int j = 0; j < 4; ++j)
                acc[i][j] = __builtin_amdgcn_mfma_f32_16x16x32_bf16(af[i], bfr[j], acc[i][j], 0, 0, 0);
        __syncthreads();
    }
    const int cq = lane >> 4;
    const int cn = lane & 15;
#pragma unroll
    for (int j = 0; j < 4; ++j) {
        int col = n0 + wc * 64 + j * 16 + cn;
        float bv = bias[col];
#pragma unroll
        for (int i = 0; i < 4; ++i) {
            int rbase = m0 + wr * 64 + i * 16 + cq * 4;
#pragma unroll
            for (int r = 0; r < 4; ++r)
                C[(size_t)(rbase + r) * N + col] = f2b(acc[i][j][r] + bv);
        }
    }
}

// ---------------------------------------------------------------------------
// K1b: bf16 MFMA GEMM (NT), fp32 OUTPUT (final out-projection).
// ---------------------------------------------------------------------------
__global__ __launch_bounds__(256) void k_gemm_mfma(
        const unsigned short* __restrict__ A, const unsigned short* __restrict__ Bw,
        const float* __restrict__ bias, float* __restrict__ C,
        int N, int K) {
    __shared__ unsigned char AsB[8192];
    __shared__ unsigned char BsB[8192];
    const int tid  = threadIdx.x;
    const int lane = tid & 63;
    const int w    = tid >> 6;
    const int wr   = w >> 1, wc = w & 1;
    const int m0 = blockIdx.y * 128, n0 = blockIdx.x * 128;
    f32x4 acc[4][4] = {};
    const int rowIn = lane >> 2;
    const int k16   = lane & 3;
    for (int k0 = 0; k0 < K; k0 += 32) {
#pragma unroll
        for (int c = 0; c < 2; ++c) {
            int chunk = w * 2 + c;
            int row = chunk * 16 + rowIn;
            const char* ga = (const char*)A  + (((size_t)(m0 + row) * K + k0) * 2) + k16 * 16;
            __builtin_amdgcn_global_load_lds(
                (const __attribute__((address_space(1))) void*)ga,
                (__attribute__((address_space(3))) void*)(AsB + chunk * 1024), 16, 0, 0);
            const char* gb = (const char*)Bw + (((size_t)(n0 + row) * K + k0) * 2) + k16 * 16;
            __builtin_amdgcn_global_load_lds(
                (const __attribute__((address_space(1))) void*)gb,
                (__attribute__((address_space(3))) void*)(BsB + chunk * 1024), 16, 0, 0);
        }
        __syncthreads();
        const int koff = (lane >> 4) * 16;
        const int rsel = lane & 15;
        bf16x8 af[4], bfr[4];
#pragma unroll
        for (int i = 0; i < 4; ++i) {
            af[i]  = *(const bf16x8*)(AsB + (wr * 64 + i * 16 + rsel) * 64 + koff);
            bfr[i] = *(const bf16x8*)(BsB + (wc * 64 + i * 16 + rsel) * 64 + koff);
        }
#pragma unroll
        for (int i = 0; i < 4; ++i)
#pragma unroll
            for (int j = 0; j < 4; ++j)
                acc[i][j] = __builtin_amdgcn_mfma_f32_16x16x32_bf16(af[i], bfr[j], acc[i][j], 0, 0, 0);
        __syncthreads();
    }
    const int cq = lane >> 4;
    const int cn = lane & 15;
#pragma unroll
    for (int j = 0; j < 4; ++j) {
        int col = n0 + wc * 64 + j * 16 + cn;
        float bv = bias[col];
#pragma unroll
        for (int i = 0; i < 4; ++i) {
            int rbase = m0 + wr * 64 + i * 16 + cq * 4;
#pragma unroll
            for (int r = 0; r < 4; ++r)
                C[(size_t)(rbase + r) * N + col] = acc[i][j][r] + bv;
        }
    }
}

// ---------------------------------------------------------------------------
// K2: depthwise short conv (k=3, causal lookback 2) + gating + transpose.
// in: x (B,L,3D) bf16 ; out: vbuf = v*x1 bf16 (B,D,L) ; x2buf = x2 bf16
// ---------------------------------------------------------------------------
__global__ __launch_bounds__(256) void k_shortconv(
        const unsigned short* __restrict__ x, const float* __restrict__ conv_w,
        const float* __restrict__ conv_b,
        unsigned short* __restrict__ vbuf, unsigned short* __restrict__ x2buf) {
    __shared__ float xs[3][32][66];
    const int l0 = blockIdx.x * 64;
    const int d0 = blockIdx.y * 32;
    const int b  = blockIdx.z;
    const int tid = threadIdx.x;
    for (int idx = tid; idx < 3 * 66 * 32; idx += 256) {
        int g  = idx / (66 * 32);
        int r  = idx % (66 * 32);
        int ll = r >> 5;
        int dd = r & 31;
        int gl = l0 - 2 + ll;
        float val = 0.f;
        if (gl >= 0) val = b2f(x[((size_t)(b * LL + gl)) * TD + g * DD + d0 + dd]);
        xs[g][dd][ll] = val;
    }
    __syncthreads();
    const int tl  = tid & 63;
    const int tdq = tid >> 6;
    for (int dd = tdq; dd < 32; dd += 4) {
        int c0 = d0 + dd;
        const float* w0 = conv_w + (size_t)c0 * 3;
        const float* w1 = conv_w + (size_t)(DD + c0) * 3;
        const float* w2 = conv_w + (size_t)(2 * DD + c0) * 3;
        float x1v = w0[0]*xs[0][dd][tl] + w0[1]*xs[0][dd][tl+1] + w0[2]*xs[0][dd][tl+2] + conv_b[c0];
        float x2v = w1[0]*xs[1][dd][tl] + w1[1]*xs[1][dd][tl+1] + w1[2]*xs[1][dd][tl+2] + conv_b[DD + c0];
        float vv  = w2[0]*xs[2][dd][tl] + w2[1]*xs[2][dd][tl+1] + w2[2]*xs[2][dd][tl+2] + conv_b[2*DD + c0];
        size_t o = ((size_t)(b * DD + c0)) * LL + l0 + tl;
        vbuf[o]  = f2b(vv * x1v);
        x2buf[o] = f2b(x2v);
    }
}

// ---------------------------------------------------------------------------
// K3a: implicit filter MLP; output TRANSPOSED h3g[16][LL]
// ---------------------------------------------------------------------------
__global__ __launch_bounds__(256) void k_filter_mlp(
        const float* __restrict__ z,
        const float* __restrict__ fw1, const float* __restrict__ fb1,
        const float* __restrict__ fw2, const float* __restrict__ fb2,
        const float* __restrict__ fw3, const float* __restrict__ fb3,
        const float* __restrict__ freq, float* __restrict__ h3g) {
    int l = blockIdx.x * 256 + threadIdx.x;
    float z0 = z[l*3+0], z1 = z[l*3+1], z2 = z[l*3+2];
    float h1[16], h2[16];
#pragma unroll
    for (int j = 0; j < 16; ++j) {
        float a = z0*fw1[j*3+0] + z1*fw1[j*3+1] + z2*fw1[j*3+2] + fb1[j];
        h1[j] = sinf(freq[j] * a);
    }
#pragma unroll
    for (int j = 0; j < 16; ++j) {
        float a = fb2[j];
#pragma unroll
        for (int i = 0; i < 16; ++i) a += h1[i] * fw2[j*16+i];
        h2[j] = sinf(freq[j] * a);
    }
#pragma unroll
    for (int j = 0; j < 16; ++j) {
        float a = fb3[j];
#pragma unroll
        for (int i = 0; i < 16; ++i) a += h2[i] * fw3[j*16+i];
        h3g[j * LL + l] = sinf(freq[j] * a);
    }
}

// ---------------------------------------------------------------------------
// K3b: fused filter construction + forward FFT; kf in engine order, 1/N and
// filter_bias folded in.
// ---------------------------------------------------------------------------
__global__ __launch_bounds__(256) void k_filter_fft(
        const float* __restrict__ h3g, const float* __restrict__ fw4,
        const float* __restrict__ fbias, float2* __restrict__ kf) {
    __shared__ float2 buf[FFT_LDS];
    const int d = blockIdx.x, t = threadIdx.x;
    float w4[16];
#pragma unroll
    for (int i = 0; i < 16; ++i) w4[i] = fw4[d * 16 + i];
    const float min_d = 3.070113457325394f;
    const float max_d = 15.35056728662697f;
    const float ad = min_d + (max_d - min_d) * ((float)d / 767.0f);
    float2 R[32];
#pragma unroll
    for (int j = 0; j < 16; ++j) {
        int l = t + 256 * j;
        float acc = 0.f;
#pragma unroll
        for (int i = 0; i < 16; ++i) acc += h3g[i * LL + l] * w4[i];
        acc *= __expf(-((float)l / 4095.0f) * ad);
        R[j] = make_float2(acc, 0.f);
        R[16 + j] = make_float2(0.f, 0.f);
    }
    eng_fwd(buf, R, t);
    const float fb = fbias[d];
    const float inv_n = 1.0f / (float)NFFT;
    float2* kd = kf + (size_t)d * NFFT;
#pragma unroll
    for (int i = 0; i < 32; ++i)
        kd[i * 256 + t] = make_float2((R[i].x + fb) * inv_n, R[i].y * inv_n);
}

// ---------------------------------------------------------------------------
// K4: packed register-FFT conv, bf16 in/out. Channels (b,d),(b+1,d) in re/im.
// Epilogue post-gates in place over x2y (bf16).
// ---------------------------------------------------------------------------
__global__ __launch_bounds__(256) void k_fftconv3(
        const unsigned short* __restrict__ vbuf, const float2* __restrict__ kf,
        unsigned short* __restrict__ x2y) {
    __shared__ float2 buf[FFT_LDS];
    const int bp = blockIdx.x;
    const int d = bp % DD;
    const int bpair = bp / DD;
    const size_t row1 = (size_t)(bpair * 2) * DD + d;
    const size_t row2 = row1 + DD;
    const unsigned short* v1 = vbuf + row1 * LL;
    const unsigned short* v2 = vbuf + row2 * LL;
    const int t = threadIdx.x;
    float2 R[32];
#pragma unroll
    for (int j = 0; j < 16; ++j) {
        int idx = t + 256 * j;
        R[j] = make_float2(b2f(v1[idx]), b2f(v2[idx]));
        R[16 + j] = make_float2(0.f, 0.f);
    }
    eng_fwd(buf, R, t);
    const float2* kd = kf + (size_t)d * NFFT;
#pragma unroll
    for (int i = 0; i < 32; ++i) {
        float2 w = kd[i * 256 + t];
        float2 zv = R[i];
        R[i] = make_float2(zv.x * w.x - zv.y * w.y, zv.x * w.y + zv.y * w.x);
    }
    eng_inv(buf, R, t);
    unsigned short* o1 = x2y + row1 * LL;
    unsigned short* o2 = x2y + row2 * LL;
#pragma unroll
    for (int j = 0; j < 16; ++j) {
        int idx = t + 256 * j;
        o1[idx] = f2b(R[j].x * b2f(o1[idx]));
        o2[idx] = f2b(R[j].y * b2f(o2[idx]));
    }
}

// ---------------------------------------------------------------------------
// K5: transpose: yg (B,D,L) bf16 -> ygT (B,L,D) bf16, 64x64 LDS tile
// ---------------------------------------------------------------------------
__global__ __launch_bounds__(256) void k_transpose_cast(
        const unsigned short* __restrict__ yg, unsigned short* __restrict__ ygT) {
    __shared__ float t[64][65];
    const int b = blockIdx.z;
    const int d0 = blockIdx.y * 64;
    const int l0 = blockIdx.x * 64;
    for (int idx = threadIdx.x; idx < 4096; idx += 256) {
        int r = idx >> 6, c = idx & 63;
        t[r][c] = b2f(yg[((size_t)(b * DD + d0 + r)) * LL + l0 + c]);
    }
    __syncthreads();
    for (int idx = threadIdx.x; idx < 2048; idx += 256) {
        int r = idx >> 5, c = (idx & 31) * 2;
        unsigned int p = (unsigned int)f2b(t[c][r]) | ((unsigned int)f2b(t[c+1][r]) << 16);
        *(unsigned int*)&ygT[((size_t)(b * LL + l0 + r)) * DD + d0 + c] = p;
    }
}

// ---------------------------------------------------------------------------
extern "C" void kernel_launch(void* const* d_in, const int* in_sizes, int n_in,
                              void* d_out, int out_size, void* d_ws, size_t ws_size,
                              hipStream_t stream) {
    const float* u      = (const float*)d_in[0];
    const float* w_in   = (const float*)d_in[1];
    const float* b_in   = (const float*)d_in[2];
    const float* w_out  = (const float*)d_in[3];
    const float* b_out  = (const float*)d_in[4];
    const float* conv_w = (const float*)d_in[5];
    const float* conv_b = (const float*)d_in[6];
    const float* z      = (const float*)d_in[7];
    const float* fw1    = (const float*)d_in[8];
    const float* fb1    = (const float*)d_in[9];
    const float* fw2    = (const float*)d_in[10];
    const float* fb2    = (const float*)d_in[11];
    const float* fw3    = (const float*)d_in[12];
    const float* fb3    = (const float*)d_in[13];
    const float* fw4    = (const float*)d_in[14];
    const float* freq   = (const float*)d_in[15];
    const float* fbias  = (const float*)d_in[16];

    char* ws = (char*)d_ws;
    // Region X [0, 75497472): x_bf (B,L,3D bf16), dead after shortconv; then:
    //   kf @ 0 (50331648), h3g @ 50331648 (262144),
    //   w_out_bf @ 50593792 (1179648), ygT @ 63176704 (25165824)
    // Region V [150994944, 176160768): vbuf bf16
    // Region Y [176160768, 201326592): x2y bf16 (in-place gated y)
    // Region U [201326592, ...): u_bf (25165824), w_in_bf @ 226492416
    unsigned short* x_bf     = (unsigned short*)(ws);
    float2* kf               = (float2*)(ws);
    float*  h3g              = (float*)(ws + 50331648);
    unsigned short* w_out_bf = (unsigned short*)(ws + 50593792);
    unsigned short* ygT      = (unsigned short*)(ws + 63176704);
    unsigned short* vbuf     = (unsigned short*)(ws + 150994944);
    unsigned short* x2y      = (unsigned short*)(ws + 176160768);
    unsigned short* u_bf     = (unsigned short*)(ws + 201326592);
    unsigned short* w_in_bf  = (unsigned short*)(ws + 226492416);

    // 0) cast u, w_in to bf16
    k_cast_pair<<<(3145728 + 442368 + 255) / 256, 256, 0, stream>>>(
        u, 3145728ULL, w_in, 442368ULL, u_bf, w_in_bf);
    // 1) x = u @ w_in^T + b_in  (bf16 MFMA, bf16 out)
    k_gemm_mfma_b16<<<dim3(TD/128, (BB*LL)/128), 256, 0, stream>>>(u_bf, w_in_bf, b_in, x_bf, TD, DD);
    // 2) short conv + pre-gate; transpose to (B,D,L) bf16
    k_shortconv<<<dim3(LL/64, DD/32, BB), 256, 0, stream>>>(x_bf, conv_w, conv_b, vbuf, x2y);
    // 3) filter: MLP -> fused (modulated k + FFT), engine-order spectrum
    k_filter_mlp<<<LL/256, 256, 0, stream>>>(z, fw1, fb1, fw2, fb2, fw3, fb3, freq, h3g);
    k_filter_fft<<<DD, 256, 0, stream>>>(h3g, fw4, fbias, kf);
    // 3b) cast w_out -> bf16
    k_cast_pair<<<(147456 + 255) / 256, 256, 0, stream>>>(
        w_out, 147456ULL, (const float*)0, 0ULL, w_out_bf, (unsigned short*)0);
    // 4) packed register-FFT long conv + post-gate (in place over x2y, bf16)
    k_fftconv3<<<(BB/2)*DD, 256, 0, stream>>>(vbuf, kf, x2y);
    // 5) transpose gated y -> (B,L,D) bf16
    k_transpose_cast<<<dim3(LL/64, DD/64, BB), 256, 0, stream>>>(x2y, ygT);
    // 6) out = ygT @ w_out^T + b_out  (bf16 MFMA, fp32 out)
    k_gemm_mfma<<<dim3(DD/128, (BB*LL)/128), 256, 0, stream>>>(ygT, w_out_bf, b_out, (float*)d_out, DD, DD);
}

// Round 6
// 427.235 us; speedup vs baseline: 3.8797x; 1.0187x over previous
//
#include <hip/hip_runtime.h>

// Problem constants
#define BB 4
#define LL 4096
#define DD 768
#define TD 2304          // 3*D
#define NFFT 8192
#define PI2 6.283185307179586f

__device__ __forceinline__ unsigned short f2b(float f) {
    unsigned u = __float_as_uint(f);
    unsigned r = (u + 0x7fffu + ((u >> 16) & 1u)) >> 16;
    return (unsigned short)r;
}
__device__ __forceinline__ float b2f(unsigned short h) {
    return __uint_as_float((unsigned)h << 16);
}

typedef __bf16 bf16x8 __attribute__((ext_vector_type(8)));
typedef float  f32x4  __attribute__((ext_vector_type(4)));

// ---------------------------------------------------------------------------
// Register FFT machinery (unchanged from round 4/5).
// ---------------------------------------------------------------------------
constexpr float TWC[16] = {
    1.f, 0.98078528f, 0.92387953f, 0.83146961f,
    0.70710678f, 0.55557023f, 0.38268343f, 0.19509032f,
    0.f, -0.19509032f, -0.38268343f, -0.55557023f,
    -0.70710678f, -0.83146961f, -0.92387953f, -0.98078528f};
constexpr float TWS[16] = {
    0.f, 0.19509032f, 0.38268343f, 0.55557023f,
    0.70710678f, 0.83146961f, 0.92387953f, 0.98078528f,
    1.f, 0.98078528f, 0.92387953f, 0.83146961f,
    0.70710678f, 0.55557023f, 0.38268343f, 0.19509032f};

template<int LOGN, bool INV>
__device__ __forceinline__ void reg_fft(float2* R) {
    constexpr int N = 1 << LOGN;
#pragma unroll
    for (int i = 0; i < N; ++i) {
        int j = 0;
#pragma unroll
        for (int b = 0; b < LOGN; ++b) if (i & (1 << b)) j |= (1 << (LOGN - 1 - b));
        if (j > i) { float2 tt = R[i]; R[i] = R[j]; R[j] = tt; }
    }
#pragma unroll
    for (int s = 1; s <= LOGN; ++s) {
        const int hm = 1 << (s - 1);
        const int tsh = 5 - s;
#pragma unroll
        for (int g = 0; g < N; g += (hm << 1)) {
#pragma unroll
            for (int j2 = 0; j2 < hm; ++j2) {
                const float wr = TWC[j2 << tsh];
                const float wi = INV ? TWS[j2 << tsh] : -TWS[j2 << tsh];
                float2 u = R[g + j2];
                float2 v = R[g + j2 + hm];
                float vr = v.x * wr - v.y * wi;
                float vi = v.x * wi + v.y * wr;
                R[g + j2]      = make_float2(u.x + vr, u.y + vi);
                R[g + j2 + hm] = make_float2(u.x - vr, u.y - vi);
            }
        }
    }
}

template<int NN>
__device__ __forceinline__ void ramp_mul(float2* R, float ang) {
    float s0, c0; __sincosf(ang, &s0, &c0);
    float wr = c0, wi = s0;
#pragma unroll
    for (int k = 1; k < NN; ++k) {
        float xr = R[k].x, xi = R[k].y;
        R[k] = make_float2(xr * wr - xi * wi, xr * wi + xi * wr);
        float nr = wr * c0 - wi * s0;
        float ni = wr * s0 + wi * c0;
        wr = nr; wi = ni;
    }
}

#define A1(t, k2) ((k2) * 288 + (t) + ((t) >> 3))
#define A2(k2, p, r) ((k2) * 272 + (r) * 17 + (p))
#define FFT_LDS 9216

__device__ __forceinline__ void eng_fwd(float2* buf, float2* R, int t) {
    reg_fft<5, false>(R);
    ramp_mul<32>(R, -PI2 * (float)t / 8192.0f);
    __syncthreads();
#pragma unroll
    for (int k2 = 0; k2 < 32; ++k2) buf[A1(t, k2)] = R[k2];
    __syncthreads();
    const int p = t & 15, c2 = (t >> 4) << 1;
#pragma unroll
    for (int q = 0; q < 16; ++q) {
        R[q]      = buf[A1(p + 16 * q, c2)];
        R[16 + q] = buf[A1(p + 16 * q, c2 + 1)];
    }
    reg_fft<4, false>(R);
    reg_fft<4, false>(R + 16);
    float a2 = -PI2 * (float)p / 256.0f;
    ramp_mul<16>(R, a2);
    ramp_mul<16>(R + 16, a2);
    __syncthreads();
#pragma unroll
    for (int r = 0; r < 16; ++r) {
        buf[A2(c2, p, r)]     = R[r];
        buf[A2(c2 + 1, p, r)] = R[16 + r];
    }
    __syncthreads();
    const int rr = p;
#pragma unroll
    for (int pp = 0; pp < 16; ++pp) {
        R[pp]      = buf[A2(c2, pp, rr)];
        R[16 + pp] = buf[A2(c2 + 1, pp, rr)];
    }
    reg_fft<4, false>(R);
    reg_fft<4, false>(R + 16);
}

__device__ __forceinline__ void eng_inv(float2* buf, float2* R, int t) {
    const int p = t & 15, c2 = (t >> 4) << 1, rr = p;
    reg_fft<4, true>(R);
    reg_fft<4, true>(R + 16);
    __syncthreads();
#pragma unroll
    for (int pp = 0; pp < 16; ++pp) {
        buf[A2(c2, pp, rr)]     = R[pp];
        buf[A2(c2 + 1, pp, rr)] = R[16 + pp];
    }
    __syncthreads();
#pragma unroll
    for (int r = 0; r < 16; ++r) {
        R[r]      = buf[A2(c2, p, r)];
        R[16 + r] = buf[A2(c2 + 1, p, r)];
    }
    float a2 = PI2 * (float)p / 256.0f;
    ramp_mul<16>(R, a2);
    ramp_mul<16>(R + 16, a2);
    reg_fft<4, true>(R);
    reg_fft<4, true>(R + 16);
    __syncthreads();
#pragma unroll
    for (int q = 0; q < 16; ++q) {
        buf[A1(p + 16 * q, c2)]     = R[q];
        buf[A1(p + 16 * q, c2 + 1)] = R[16 + q];
    }
    __syncthreads();
#pragma unroll
    for (int k2 = 0; k2 < 32; ++k2) R[k2] = buf[A1(t, k2)];
    ramp_mul<32>(R, PI2 * (float)t / 8192.0f);
    reg_fft<5, true>(R);
}

// ---------------------------------------------------------------------------
// K0: fp32 -> bf16 cast (two sources fused), float4 granularity
// ---------------------------------------------------------------------------
__global__ __launch_bounds__(256) void k_cast_pair(
        const float* __restrict__ srcA, unsigned long long nA4,
        const float* __restrict__ srcB, unsigned long long nB4,
        unsigned short* __restrict__ dstA, unsigned short* __restrict__ dstB) {
    unsigned long long i = (unsigned long long)blockIdx.x * 256 + threadIdx.x;
    const float* s; unsigned short* d;
    if (i < nA4)            { s = srcA + i * 4;         d = dstA + i * 4; }
    else if (i < nA4 + nB4) { unsigned long long j = i - nA4; s = srcB + j * 4; d = dstB + j * 4; }
    else return;
    float4 v = *(const float4*)s;
    unsigned long long p = (unsigned long long)f2b(v.x)
                         | ((unsigned long long)f2b(v.y) << 16)
                         | ((unsigned long long)f2b(v.z) << 32)
                         | ((unsigned long long)f2b(v.w) << 48);
    *(unsigned long long*)d = p;
}

// ---------------------------------------------------------------------------
// GEMM core (NT, bf16 MFMA): BK=64, XOR-swizzled 16B slots.
// LDS: A,B tiles 128 rows x 128 B (16 KB each). Staging: 8 global_load_lds
// per thread per iter; lane fetches global slot (lane&7)^(row&7) so readers
// un-swizzle to hit all 32 banks (2-way = free).
// ---------------------------------------------------------------------------
#define GEMM_BODY(EPILOGUE)                                                     \
    __shared__ unsigned char AsB[16384];                                        \
    __shared__ unsigned char BsB[16384];                                        \
    const int tid  = threadIdx.x;                                               \
    const int lane = tid & 63;                                                  \
    const int w    = tid >> 6;                                                  \
    const int wr   = w >> 1, wc = w & 1;                                        \
    const int m0 = blockIdx.y * 128, n0 = blockIdx.x * 128;                     \
    f32x4 acc[4][4] = {};                                                       \
    const int srow = lane >> 3;          /* 0..7 within 8-row chunk */          \
    const int sslot = (lane & 7) ^ srow; /* swizzled global 16B slot */         \
    for (int k0 = 0; k0 < K; k0 += 64) {                                        \
        _Pragma("unroll")                                                       \
        for (int c = 0; c < 4; ++c) {                                           \
            int chunk = w * 4 + c;                                              \
            int row = chunk * 8 + srow;                                         \
            const char* ga = (const char*)A  + (((size_t)(m0 + row) * K + k0) * 2) + sslot * 16; \
            __builtin_amdgcn_global_load_lds(                                   \
                (const __attribute__((address_space(1))) void*)ga,              \
                (__attribute__((address_space(3))) void*)(AsB + chunk * 1024), 16, 0, 0); \
            const char* gb = (const char*)Bw + (((size_t)(n0 + row) * K + k0) * 2) + sslot * 16; \
            __builtin_amdgcn_global_load_lds(                                   \
                (const __attribute__((address_space(1))) void*)gb,              \
                (__attribute__((address_space(3))) void*)(BsB + chunk * 1024), 16, 0, 0); \
        }                                                                       \
        __syncthreads();                                                        \
        const int quad = lane >> 4;                                             \
        const int rsel = lane & 15;                                             \
        _Pragma("unroll")                                                       \
        for (int kk = 0; kk < 2; ++kk) {                                        \
            bf16x8 af[4], bfr[4];                                               \
            _Pragma("unroll")                                                   \
            for (int i = 0; i < 4; ++i) {                                       \
                int rowA = wr * 64 + i * 16 + rsel;                             \
                int slotA = (kk * 4 + quad) ^ (rsel & 7);                       \
                af[i]  = *(const bf16x8*)(AsB + rowA * 128 + slotA * 16);       \
                int rowB = wc * 64 + i * 16 + rsel;                             \
                bfr[i] = *(const bf16x8*)(BsB + rowB * 128 + slotA * 16);       \
            }                                                                   \
            _Pragma("unroll")                                                   \
            for (int i = 0; i < 4; ++i)                                         \
                _Pragma("unroll")                                               \
                for (int j = 0; j < 4; ++j)                                     \
                    acc[i][j] = __builtin_amdgcn_mfma_f32_16x16x32_bf16(af[i], bfr[j], acc[i][j], 0, 0, 0); \
        }                                                                       \
        __syncthreads();                                                        \
    }                                                                           \
    const int cq = lane >> 4;                                                   \
    const int cn = lane & 15;                                                   \
    _Pragma("unroll")                                                           \
    for (int j = 0; j < 4; ++j) {                                               \
        int col = n0 + wc * 64 + j * 16 + cn;                                   \
        float bv = bias[col];                                                   \
        _Pragma("unroll")                                                       \
        for (int i = 0; i < 4; ++i) {                                           \
            int rbase = m0 + wr * 64 + i * 16 + cq * 4;                         \
            _Pragma("unroll")                                                   \
            for (int r = 0; r < 4; ++r)                                         \
                EPILOGUE;                                                       \
        }                                                                       \
    }

__global__ __launch_bounds__(256) void k_gemm_mfma_b16(
        const unsigned short* __restrict__ A, const unsigned short* __restrict__ Bw,
        const float* __restrict__ bias, unsigned short* __restrict__ C,
        int N, int K) {
    GEMM_BODY(C[(size_t)(rbase + r) * N + col] = f2b(acc[i][j][r] + bv))
}

__global__ __launch_bounds__(256) void k_gemm_mfma(
        const unsigned short* __restrict__ A, const unsigned short* __restrict__ Bw,
        const float* __restrict__ bias, float* __restrict__ C,
        int N, int K) {
    GEMM_BODY(C[(size_t)(rbase + r) * N + col] = acc[i][j][r] + bv)
}

// ---------------------------------------------------------------------------
// K2: depthwise short conv (k=3, causal lookback 2) + gating + transpose.
// in: x (B,L,3D) bf16 ; out: vbuf = v*x1 bf16 (B,D,L) ; x2buf = x2 bf16
// ---------------------------------------------------------------------------
__global__ __launch_bounds__(256) void k_shortconv(
        const unsigned short* __restrict__ x, const float* __restrict__ conv_w,
        const float* __restrict__ conv_b,
        unsigned short* __restrict__ vbuf, unsigned short* __restrict__ x2buf) {
    __shared__ float xs[3][32][66];
    const int l0 = blockIdx.x * 64;
    const int d0 = blockIdx.y * 32;
    const int b  = blockIdx.z;
    const int tid = threadIdx.x;
    for (int idx = tid; idx < 3 * 66 * 16; idx += 256) {
        int g  = idx / (66 * 16);
        int r  = idx % (66 * 16);
        int ll = r >> 4;
        int dd2 = (r & 15) * 2;
        int gl = l0 - 2 + ll;
        float v0 = 0.f, v1 = 0.f;
        if (gl >= 0) {
            unsigned int pk = *(const unsigned int*)&x[((size_t)(b * LL + gl)) * TD + g * DD + d0 + dd2];
            v0 = b2f((unsigned short)(pk & 0xffffu));
            v1 = b2f((unsigned short)(pk >> 16));
        }
        xs[g][dd2][ll] = v0;
        xs[g][dd2 + 1][ll] = v1;
    }
    __syncthreads();
    const int tl  = tid & 63;
    const int tdq = tid >> 6;
    for (int dd = tdq; dd < 32; dd += 4) {
        int c0 = d0 + dd;
        const float* w0 = conv_w + (size_t)c0 * 3;
        const float* w1 = conv_w + (size_t)(DD + c0) * 3;
        const float* w2 = conv_w + (size_t)(2 * DD + c0) * 3;
        float x1v = w0[0]*xs[0][dd][tl] + w0[1]*xs[0][dd][tl+1] + w0[2]*xs[0][dd][tl+2] + conv_b[c0];
        float x2v = w1[0]*xs[1][dd][tl] + w1[1]*xs[1][dd][tl+1] + w1[2]*xs[1][dd][tl+2] + conv_b[DD + c0];
        float vv  = w2[0]*xs[2][dd][tl] + w2[1]*xs[2][dd][tl+1] + w2[2]*xs[2][dd][tl+2] + conv_b[2*DD + c0];
        size_t o = ((size_t)(b * DD + c0)) * LL + l0 + tl;
        vbuf[o]  = f2b(vv * x1v);
        x2buf[o] = f2b(x2v);
    }
}

// ---------------------------------------------------------------------------
// K3a: implicit filter MLP; output TRANSPOSED h3g[16][LL]
// ---------------------------------------------------------------------------
__global__ __launch_bounds__(256) void k_filter_mlp(
        const float* __restrict__ z,
        const float* __restrict__ fw1, const float* __restrict__ fb1,
        const float* __restrict__ fw2, const float* __restrict__ fb2,
        const float* __restrict__ fw3, const float* __restrict__ fb3,
        const float* __restrict__ freq, float* __restrict__ h3g) {
    int l = blockIdx.x * 256 + threadIdx.x;
    float z0 = z[l*3+0], z1 = z[l*3+1], z2 = z[l*3+2];
    float h1[16], h2[16];
#pragma unroll
    for (int j = 0; j < 16; ++j) {
        float a = z0*fw1[j*3+0] + z1*fw1[j*3+1] + z2*fw1[j*3+2] + fb1[j];
        h1[j] = sinf(freq[j] * a);
    }
#pragma unroll
    for (int j = 0; j < 16; ++j) {
        float a = fb2[j];
#pragma unroll
        for (int i = 0; i < 16; ++i) a += h1[i] * fw2[j*16+i];
        h2[j] = sinf(freq[j] * a);
    }
#pragma unroll
    for (int j = 0; j < 16; ++j) {
        float a = fb3[j];
#pragma unroll
        for (int i = 0; i < 16; ++i) a += h2[i] * fw3[j*16+i];
        h3g[j * LL + l] = sinf(freq[j] * a);
    }
}

// ---------------------------------------------------------------------------
// K3b: fused filter construction + forward FFT; kf in engine order, 1/N and
// filter_bias folded in.
// ---------------------------------------------------------------------------
__global__ __launch_bounds__(256) void k_filter_fft(
        const float* __restrict__ h3g, const float* __restrict__ fw4,
        const float* __restrict__ fbias, float2* __restrict__ kf) {
    __shared__ float2 buf[FFT_LDS];
    const int d = blockIdx.x, t = threadIdx.x;
    float w4[16];
#pragma unroll
    for (int i = 0; i < 16; ++i) w4[i] = fw4[d * 16 + i];
    const float min_d = 3.070113457325394f;
    const float max_d = 15.35056728662697f;
    const float ad = min_d + (max_d - min_d) * ((float)d / 767.0f);
    float2 R[32];
#pragma unroll
    for (int j = 0; j < 16; ++j) {
        int l = t + 256 * j;
        float acc = 0.f;
#pragma unroll
        for (int i = 0; i < 16; ++i) acc += h3g[i * LL + l] * w4[i];
        acc *= __expf(-((float)l / 4095.0f) * ad);
        R[j] = make_float2(acc, 0.f);
        R[16 + j] = make_float2(0.f, 0.f);
    }
    eng_fwd(buf, R, t);
    const float fb = fbias[d];
    const float inv_n = 1.0f / (float)NFFT;
    float2* kd = kf + (size_t)d * NFFT;
#pragma unroll
    for (int i = 0; i < 32; ++i)
        kd[i * 256 + t] = make_float2((R[i].x + fb) * inv_n, R[i].y * inv_n);
}

// ---------------------------------------------------------------------------
// K4: packed register-FFT conv, bf16 in/out.
// ---------------------------------------------------------------------------
__global__ __launch_bounds__(256) void k_fftconv3(
        const unsigned short* __restrict__ vbuf, const float2* __restrict__ kf,
        unsigned short* __restrict__ x2y) {
    __shared__ float2 buf[FFT_LDS];
    const int bp = blockIdx.x;
    const int d = bp % DD;
    const int bpair = bp / DD;
    const size_t row1 = (size_t)(bpair * 2) * DD + d;
    const size_t row2 = row1 + DD;
    const unsigned short* v1 = vbuf + row1 * LL;
    const unsigned short* v2 = vbuf + row2 * LL;
    const int t = threadIdx.x;
    float2 R[32];
#pragma unroll
    for (int j = 0; j < 16; ++j) {
        int idx = t + 256 * j;
        R[j] = make_float2(b2f(v1[idx]), b2f(v2[idx]));
        R[16 + j] = make_float2(0.f, 0.f);
    }
    eng_fwd(buf, R, t);
    const float2* kd = kf + (size_t)d * NFFT;
#pragma unroll
    for (int i = 0; i < 32; ++i) {
        float2 w = kd[i * 256 + t];
        float2 zv = R[i];
        R[i] = make_float2(zv.x * w.x - zv.y * w.y, zv.x * w.y + zv.y * w.x);
    }
    eng_inv(buf, R, t);
    unsigned short* o1 = x2y + row1 * LL;
    unsigned short* o2 = x2y + row2 * LL;
#pragma unroll
    for (int j = 0; j < 16; ++j) {
        int idx = t + 256 * j;
        o1[idx] = f2b(R[j].x * b2f(o1[idx]));
        o2[idx] = f2b(R[j].y * b2f(o2[idx]));
    }
}

// ---------------------------------------------------------------------------
// K5: transpose: yg (B,D,L) bf16 -> ygT (B,L,D) bf16, 64x64 LDS tile
// ---------------------------------------------------------------------------
__global__ __launch_bounds__(256) void k_transpose_cast(
        const unsigned short* __restrict__ yg, unsigned short* __restrict__ ygT) {
    __shared__ float t[64][65];
    const int b = blockIdx.z;
    const int d0 = blockIdx.y * 64;
    const int l0 = blockIdx.x * 64;
    for (int idx = threadIdx.x; idx < 4096; idx += 256) {
        int r = idx >> 6, c = idx & 63;
        t[r][c] = b2f(yg[((size_t)(b * DD + d0 + r)) * LL + l0 + c]);
    }
    __syncthreads();
    for (int idx = threadIdx.x; idx < 2048; idx += 256) {
        int r = idx >> 5, c = (idx & 31) * 2;
        unsigned int p = (unsigned int)f2b(t[c][r]) | ((unsigned int)f2b(t[c+1][r]) << 16);
        *(unsigned int*)&ygT[((size_t)(b * LL + l0 + r)) * DD + d0 + c] = p;
    }
}

// ---------------------------------------------------------------------------
extern "C" void kernel_launch(void* const* d_in, const int* in_sizes, int n_in,
                              void* d_out, int out_size, void* d_ws, size_t ws_size,
                              hipStream_t stream) {
    const float* u      = (const float*)d_in[0];
    const float* w_in   = (const float*)d_in[1];
    const float* b_in   = (const float*)d_in[2];
    const float* w_out  = (const float*)d_in[3];
    const float* b_out  = (const float*)d_in[4];
    const float* conv_w = (const float*)d_in[5];
    const float* conv_b = (const float*)d_in[6];
    const float* z      = (const float*)d_in[7];
    const float* fw1    = (const float*)d_in[8];
    const float* fb1    = (const float*)d_in[9];
    const float* fw2    = (const float*)d_in[10];
    const float* fb2    = (const float*)d_in[11];
    const float* fw3    = (const float*)d_in[12];
    const float* fb3    = (const float*)d_in[13];
    const float* fw4    = (const float*)d_in[14];
    const float* freq   = (const float*)d_in[15];
    const float* fbias  = (const float*)d_in[16];

    char* ws = (char*)d_ws;
    unsigned short* x_bf     = (unsigned short*)(ws);
    float2* kf               = (float2*)(ws);
    float*  h3g              = (float*)(ws + 50331648);
    unsigned short* w_out_bf = (unsigned short*)(ws + 50593792);
    unsigned short* ygT      = (unsigned short*)(ws + 63176704);
    unsigned short* vbuf     = (unsigned short*)(ws + 150994944);
    unsigned short* x2y      = (unsigned short*)(ws + 176160768);
    unsigned short* u_bf     = (unsigned short*)(ws + 201326592);
    unsigned short* w_in_bf  = (unsigned short*)(ws + 226492416);

    // 0) cast u, w_in to bf16
    k_cast_pair<<<(3145728 + 442368 + 255) / 256, 256, 0, stream>>>(
        u, 3145728ULL, w_in, 442368ULL, u_bf, w_in_bf);
    // 1) x = u @ w_in^T + b_in  (bf16 MFMA, bf16 out, BK=64)
    k_gemm_mfma_b16<<<dim3(TD/128, (BB*LL)/128), 256, 0, stream>>>(u_bf, w_in_bf, b_in, x_bf, TD, DD);
    // 2) short conv + pre-gate; transpose to (B,D,L) bf16
    k_shortconv<<<dim3(LL/64, DD/32, BB), 256, 0, stream>>>(x_bf, conv_w, conv_b, vbuf, x2y);
    // 3) filter: MLP -> fused (modulated k + FFT), engine-order spectrum
    k_filter_mlp<<<LL/256, 256, 0, stream>>>(z, fw1, fb1, fw2, fb2, fw3, fb3, freq, h3g);
    k_filter_fft<<<DD, 256, 0, stream>>>(h3g, fw4, fbias, kf);
    // 3b) cast w_out -> bf16
    k_cast_pair<<<(147456 + 255) / 256, 256, 0, stream>>>(
        w_out, 147456ULL, (const float*)0, 0ULL, w_out_bf, (unsigned short*)0);
    // 4) packed register-FFT long conv + post-gate (in place over x2y, bf16)
    k_fftconv3<<<(BB/2)*DD, 256, 0, stream>>>(vbuf, kf, x2y);
    // 5) transpose gated y -> (B,L,D) bf16
    k_transpose_cast<<<dim3(LL/64, DD/64, BB), 256, 0, stream>>>(x2y, ygT);
    // 6) out = ygT @ w_out^T + b_out  (bf16 MFMA, fp32 out, BK=64)
    k_gemm_mfma<<<dim3(DD/128, (BB*LL)/128), 256, 0, stream>>>(ygT, w_out_bf, b_out, (float*)d_out, DD, DD);
}